// Round 11
// baseline (5778.772 us; speedup 1.0000x reference)
//
#include <hip/hip_runtime.h>
#include <hip/hip_bf16.h>
#include <math.h>

#define H    1024
#define NST  64
#define LAYN 2
#define BSZ  32
#define TLEN 512
#define NSTEPS 16
#define H2   2048

typedef __attribute__((ext_vector_type(8))) short bf16x8;
typedef __attribute__((ext_vector_type(4))) float f32x4;

__device__ __forceinline__ float gelu_f(float x){
    return 0.5f*x*(1.0f+erff(x*0.7071067811865475f));
}
__device__ __forceinline__ float sigm_f(float x){
    return 1.0f/(1.0f+expf(-x));
}
__device__ __forceinline__ short bfbits(float x){
    __hip_bfloat16 h = __float2bfloat16(x);
    return *(short*)&h;
}
__device__ __forceinline__ void gload16(const void* g, void* l){
    __builtin_amdgcn_global_load_lds((const __attribute__((address_space(1))) void*)g,
                                     (__attribute__((address_space(3))) void*)l, 16, 0, 0);
}

// ---------------- discretized SSM params ----------------
__global__ void k_precompute(const float* __restrict__ log_dt,
                             const float* __restrict__ Are, const float* __restrict__ Aim,
                             const float* __restrict__ Bre, const float* __restrict__ Bim,
                             float* __restrict__ dAr, float* __restrict__ dAi,
                             float* __restrict__ dBr, float* __restrict__ dBi){
    int i = blockIdx.x*256 + threadIdx.x;
    if (i >= LAYN*H*NST) return;
    int lh = i / NST;
    float dt = expf(log_dt[lh]);
    float ar = Are[i], ai = Aim[i];
    float e  = expf(dt*ar);
    float sa, ca; sincosf(dt*ai, &sa, &ca);
    float dar = e*ca, dai = e*sa;
    float zr = dar-1.0f, zi = dai;
    float inv = 1.0f/(ar*ar + ai*ai);
    float wr = (zr*ar + zi*ai)*inv;
    float wi = (zi*ar - zr*ai)*inv;
    float br = Bre[i], bi = Bim[i];
    dAr[i]=dar; dAi[i]=dai;
    dBr[i]=wr*br - wi*bi;
    dBi[i]=wr*bi + wi*br;
}

// ---------------- in_proj ----------------
__global__ void k_inproj_x(const float* __restrict__ in, const float* __restrict__ w,
                           const float* __restrict__ bias, float* __restrict__ x){
    int i = blockIdx.x*256+threadIdx.x;          // b*T*H + t*H + h
    int h = i & (H-1);
    int bt = i >> 10;
    x[i] = in[bt]*w[h] + bias[h];
}
__global__ void k_inproj_xT(const float* __restrict__ in, const float* __restrict__ w,
                            const float* __restrict__ bias, float* __restrict__ xT){
    int i = blockIdx.x*256+threadIdx.x;          // b*H*T + h*T + t
    int t = i & (TLEN-1);
    int bh = i >> 9;
    int h = bh & (H-1);
    int b = bh >> 10;
    xT[i] = in[b*TLEN + t]*w[h] + bias[h];
}

// ---------------- S4 conv kernel gen ----------------
__global__ __launch_bounds__(64) void k_genK(
        const float* __restrict__ dAr, const float* __restrict__ dAi,
        const float* __restrict__ dBr, const float* __restrict__ dBi,
        const float* __restrict__ Cre, const float* __restrict__ Cim,
        float* __restrict__ Kbuf){
    __shared__ float trans[16][65];
    int lh = blockIdx.x;
    int lane = threadIdx.x;
    int pi = lh*NST + lane;
    float ar=dAr[pi], ai=dAi[pi];
    float br=dBr[pi], bi=dBi[pi];
    float cr=2.f*Cre[pi], ci=2.f*Cim[pi];
    float wr = cr*br - ci*bi;
    float wi = cr*bi + ci*br;
    float* Krow = Kbuf + (size_t)lh*TLEN;
    int r = lane>>2, q = lane&3;
    for (int c=0;c<TLEN/16;c++){
        #pragma unroll
        for (int i=0;i<16;i++){
            trans[i][lane] = wr;
            float nr = fmaf(wr,ar, -wi*ai);
            float ni = fmaf(wr,ai,  wi*ar);
            wr=nr; wi=ni;
        }
        __syncthreads();
        float s = 0.f;
        #pragma unroll
        for (int m=0;m<16;m++) s += trans[r][q*16+m];
        s += __shfl_xor(s,1,64);
        s += __shfl_xor(s,2,64);
        if (q==0) Krow[c*16 + r] = s;
        __syncthreads();
    }
}

// ---------------- causal Toeplitz conv + D*u + gelu; bf16 (B,H,T) out ----------------
#define CTT 256
#define CJT 64
__global__ __launch_bounds__(256) void k_conv(
        const float* __restrict__ u,            // (B,H,T) f32
        const float* __restrict__ Kbuf,         // (L,H,T)
        const float* __restrict__ Dv,
        __hip_bfloat16* __restrict__ g,         // (B,H,T) bf16
        int layer){
    __shared__ float u_s[CJT][33];
    __shared__ float Ks[CTT+CJT];
    int h  = blockIdx.y;
    int t0 = blockIdx.x * CTT;
    int tid = threadIdx.x;
    int bg = tid & 7;
    int tg = tid >> 3;
    const float* Krow = Kbuf + ((size_t)layer*H + h)*TLEN;
    float acc[8][4];
    #pragma unroll
    for (int i=0;i<8;i++){
        #pragma unroll
        for (int b=0;b<4;b++) acc[i][b]=0.f;
    }
    int ntile = t0/CJT + CTT/CJT;
    for (int jt=0; jt<ntile; jt++){
        int j0 = jt*CJT;
        __syncthreads();
        for (int i=tid; i<CTT+CJT; i+=256){
            int d = t0 - j0 - (CJT-1) + i;
            Ks[i] = (d>=0) ? Krow[d] : 0.f;
        }
        {
            int jj = tid & 63, bq = tid >> 6;
            #pragma unroll
            for (int p=0;p<8;p++){
                int b = bq + p*4;
                u_s[jj][b] = u[((size_t)b*H + h)*TLEN + j0 + jj];
            }
        }
        __syncthreads();
        #pragma unroll 8
        for (int j=0;j<CJT;j++){
            float4 ub = *(const float4*)&u_s[j][bg*4];
            int base = tg*8 + (CJT-1) - j;
            float kv[8];
            #pragma unroll
            for (int i=0;i<8;i++) kv[i] = Ks[base+i];
            #pragma unroll
            for (int i=0;i<8;i++){
                acc[i][0] = fmaf(kv[i], ub.x, acc[i][0]);
                acc[i][1] = fmaf(kv[i], ub.y, acc[i][1]);
                acc[i][2] = fmaf(kv[i], ub.z, acc[i][2]);
                acc[i][3] = fmaf(kv[i], ub.w, acc[i][3]);
            }
        }
    }
    float dv = Dv[layer*H + h];
    int tb = t0 + tg*8;
    #pragma unroll
    for (int b=0;b<4;b++){
        int bb = bg*4 + b;
        const float* urow = u + ((size_t)bb*H + h)*TLEN + tb;
        float4 u0 = *(const float4*)urow;
        float4 u1 = *(const float4*)(urow+4);
        bf16x8 o;
        o[0] = bfbits(gelu_f(fmaf(dv,u0.x, acc[0][b])));
        o[1] = bfbits(gelu_f(fmaf(dv,u0.y, acc[1][b])));
        o[2] = bfbits(gelu_f(fmaf(dv,u0.z, acc[2][b])));
        o[3] = bfbits(gelu_f(fmaf(dv,u0.w, acc[3][b])));
        o[4] = bfbits(gelu_f(fmaf(dv,u1.x, acc[4][b])));
        o[5] = bfbits(gelu_f(fmaf(dv,u1.y, acc[5][b])));
        o[6] = bfbits(gelu_f(fmaf(dv,u1.z, acc[6][b])));
        o[7] = bfbits(gelu_f(fmaf(dv,u1.w, acc[7][b])));
        *(bf16x8*)(g + ((size_t)bb*H + h)*TLEN + tb) = o;
    }
}

// ---------------- bf16 transpose (B,H,T) -> (B,T,H) ----------------
__global__ __launch_bounds__(256) void k_trcast_bf(const __hip_bfloat16* __restrict__ x,
                                                   __hip_bfloat16* __restrict__ y){
    __shared__ __hip_bfloat16 tile[32][34];
    int t0 = blockIdx.x*32, h0 = blockIdx.y*32, b = blockIdx.z;
    int tx = threadIdx.x & 31, ty = threadIdx.x >> 5;
    #pragma unroll
    for (int i=0;i<32;i+=8)
        tile[ty+i][tx] = x[((size_t)(b*H + h0+ty+i))*TLEN + t0+tx];
    __syncthreads();
    #pragma unroll
    for (int i=0;i<32;i+=8)
        y[((size_t)(b*TLEN + t0+ty+i))*H + h0+tx] = tile[tx][ty+i];
}

// ---------------- transpose (b,t,h) -> (b,h,t) f32 ----------------
__global__ __launch_bounds__(256) void k_transpose(const float* __restrict__ x, float* __restrict__ xT){
    __shared__ float tile[32][33];
    int t0 = blockIdx.x*32, h0 = blockIdx.y*32, b = blockIdx.z;
    int tx = threadIdx.x & 31, ty = threadIdx.x >> 5;
    #pragma unroll
    for (int i=0;i<32;i+=8)
        tile[ty+i][tx] = x[((size_t)(b*TLEN + t0+ty+i))*H + h0+tx];
    __syncthreads();
    #pragma unroll
    for (int i=0;i<32;i+=8)
        xT[((size_t)(b*H + h0+ty+i))*TLEN + t0+tx] = tile[tx][ty+i];
}

// ---------------- W (L,H,2H) f32 -> Wt (L,2H,H) bf16 (encoder GEMM B operand) ----------------
__global__ __launch_bounds__(256) void k_wtr(const float* __restrict__ W,
                                             __hip_bfloat16* __restrict__ Wt){
    __shared__ float tile[32][33];
    int n0 = blockIdx.x*32, k0 = blockIdx.y*32, l = blockIdx.z;
    const float* Wl = W + (size_t)l*H*H2;
    __hip_bfloat16* Wtl = Wt + (size_t)l*H*H2;
    int tx = threadIdx.x & 31, ty = threadIdx.x >> 5;
    #pragma unroll
    for (int i=0;i<32;i+=8)
        tile[ty+i][tx] = Wl[(size_t)(k0+ty+i)*H2 + n0+tx];
    __syncthreads();
    #pragma unroll
    for (int i=0;i<32;i+=8)
        Wtl[(size_t)(n0+ty+i)*H + k0+tx] = __float2bfloat16(tile[tx][ty+i]);
}

// ---------------- bf16 MFMA GEMM + bias + GLU fused (encoder) ----------------
__global__ __launch_bounds__(256) void k_gemm_glu_mfma(
        const __hip_bfloat16* __restrict__ Abf,
        const __hip_bfloat16* __restrict__ Wt,
        const float* __restrict__ bias2,         // (2048,)
        float* __restrict__ glu){                // (M,1024)
    __shared__ alignas(16) short As[128*32];
    __shared__ alignas(16) short Bs[128*32];
    const int K = 1024;
    int tid = threadIdx.x;
    int lane = tid & 63, wid = tid >> 6;
    int m0 = blockIdx.x * 128;
    int nb = blockIdx.y * 64;
    int g0 = tid, g1 = tid + 256;
    int r0 = g0 >> 2, r1 = g1 >> 2;
    int wtr0 = nb + ((r0>>6)<<5) + (r0&31) + ((r0>>5)&1)*1024;
    int wtr1 = nb + ((r1>>6)<<5) + (r1&31) + ((r1>>5)&1)*1024;
    const short* Ap = (const short*)Abf;
    const short* Bp = (const short*)Wt;
    const short* Ag0 = Ap + (size_t)(m0 + r0)*K + (g0&3)*8;
    const short* Ag1 = Ap + (size_t)(m0 + r1)*K + (g1&3)*8;
    const short* Bg0 = Bp + (size_t)wtr0*K + (g0&3)*8;
    const short* Bg1 = Bp + (size_t)wtr1*K + (g1&3)*8;
    char* AsB = (char*)As;
    char* BsB = (char*)Bs;
    int wr = wid >> 1, wc = wid & 1;
    int mo = wr*64, no = wc*64;
    f32x4 acc[4][4] = {};
    int arow = (lane & 15)*32 + (lane>>4)*8;
    for (int k0 = 0; k0 < K; k0 += 32){
        gload16(Ag0 + k0, AsB + wid*1024);
        gload16(Ag1 + k0, AsB + 4096 + wid*1024);
        gload16(Bg0 + k0, BsB + wid*1024);
        gload16(Bg1 + k0, BsB + 4096 + wid*1024);
        asm volatile("s_waitcnt vmcnt(0)" ::: "memory");
        __syncthreads();
        bf16x8 a[4], b[4];
        #pragma unroll
        for (int mi=0;mi<4;mi++)
            a[mi] = *(const bf16x8*)(As + (mo + mi*16)*32 + arow);
        #pragma unroll
        for (int ni=0;ni<4;ni++)
            b[ni] = *(const bf16x8*)(Bs + (no + ni*16)*32 + arow);
        #pragma unroll
        for (int mi=0;mi<4;mi++){
            #pragma unroll
            for (int ni=0;ni<4;ni++){
                acc[mi][ni] = __builtin_amdgcn_mfma_f32_16x16x32_bf16(a[mi], b[ni], acc[mi][ni], 0, 0, 0);
            }
        }
        __syncthreads();
    }
    int cbase = nb + wc*32 + (lane&15);
    #pragma unroll
    for (int ni=0;ni<2;ni++){
        int c = cbase + ni*16;
        float ba = bias2[c], bb = bias2[c+1024];
        #pragma unroll
        for (int mi=0;mi<4;mi++){
            #pragma unroll
            for (int r=0;r<4;r++){
                size_t m = m0 + mo + mi*16 + (lane>>4)*4 + r;
                float za = acc[mi][ni][r] + ba;
                float zb = acc[mi][ni+2][r] + bb;
                glu[m*H + c] = za * sigm_f(zb);
            }
        }
    }
}

// ---------------- LayerNorm over H per (b,t) row (encoder) ----------------
__global__ __launch_bounds__(256) void k_ln(const float* __restrict__ glu, const float* __restrict__ res,
        const float* __restrict__ gamma, const float* __restrict__ beta, float* __restrict__ outx){
    __shared__ float red[8];
    int row = blockIdx.x;
    int tid = threadIdx.x;
    float4 gv = *(const float4*)(glu + (size_t)row*H + tid*4);
    float4 rv = *(const float4*)(res + (size_t)row*H + tid*4);
    float x0=gv.x+rv.x, x1=gv.y+rv.y, x2=gv.z+rv.z, x3=gv.w+rv.w;
    float s = x0+x1+x2+x3;
    float q = x0*x0+x1*x1+x2*x2+x3*x3;
    #pragma unroll
    for (int m=32;m>=1;m>>=1){ s += __shfl_xor(s,m,64); q += __shfl_xor(q,m,64); }
    int wv = tid>>6;
    if ((tid&63)==0){ red[wv]=s; red[4+wv]=q; }
    __syncthreads();
    s = red[0]+red[1]+red[2]+red[3];
    q = red[4]+red[5]+red[6]+red[7];
    float m = s*(1.0f/H);
    float v = q*(1.0f/H) - m*m;
    float rstd = rsqrtf(v + 1e-5f);
    float4 gm = *(const float4*)(gamma + tid*4);
    float4 bt = *(const float4*)(beta + tid*4);
    float4 o;
    o.x = (x0-m)*rstd*gm.x + bt.x;
    o.y = (x1-m)*rstd*gm.y + bt.y;
    o.z = (x2-m)*rstd*gm.z + bt.z;
    o.w = (x3-m)*rstd*gm.w + bt.w;
    *(float4*)(outx + (size_t)row*H + tid*4) = o;
}

__global__ void k_ctx(const float* __restrict__ x, float* __restrict__ ctx){
    int i = blockIdx.x*256+threadIdx.x;
    int b = i>>10, h = i&(H-1);
    ctx[i] = x[((size_t)(b*TLEN + TLEN-1))*H + h];
}

// ======================= BATCH-PARALLEL DECODE (zero global barriers) =======================
// One block per batch (32 blocks x 1024 threads; thread = h). The SSM recurrence
// with s0=0 over 16 steps == 16-tap causal conv with Kbuf -> u-history shift
// registers (compile-time indices). All cross-phase data in LDS; sync = __syncthreads.
__global__ __launch_bounds__(1024, 4) void k_decode(
        const float* __restrict__ Kbuf, const float* __restrict__ Dv,
        const float* __restrict__ W, const float* __restrict__ bias2,
        const float* __restrict__ lng, const float* __restrict__ lnb,
        const float* __restrict__ ctx, const float* __restrict__ headw,
        const float* __restrict__ headb, float* __restrict__ out){
    __shared__ float ysh[H];
    __shared__ float red[32];
    int b = blockIdx.x, t = threadIdx.x;
    int wv = t >> 6, lane = t & 63;
    // step-invariant per-h parameters (registers)
    float K0[16], K1[16];
    #pragma unroll
    for (int d=0; d<16; d++){
        K0[d] = Kbuf[(size_t)t*TLEN + d];
        K1[d] = Kbuf[(size_t)(H + t)*TLEN + d];
    }
    float dv0 = Dv[t], dv1 = Dv[H+t];
    float g0 = lng[t], be0 = lnb[t], g1 = lng[H+t], be1 = lnb[H+t];
    float cv = ctx[b*H + t], hw = headw[t], hb = headb[0];
    float ba0 = bias2[t],     bb0 = bias2[H+t];
    float ba1 = bias2[H2+t],  bb1 = bias2[H2+H+t];
    const float* W0 = W + t;
    const float* W1 = W + (size_t)H*H2 + t;
    float u0h[16], u1h[16];
    #pragma unroll
    for (int j=0;j<16;j++){ u0h[j]=0.f; u1h[j]=0.f; }
    float bit = 0.f;
    for (int step=0; step<NSTEPS; step++){
        // ---- layer 0: 16-tap conv y0 (u0 = broadcast bit history) ----
        #pragma unroll
        for (int j=0;j<15;j++) u0h[j] = u0h[j+1];
        u0h[15] = bit;
        float y0 = dv0 * bit;
        #pragma unroll
        for (int d=0; d<16; d++) y0 = fmaf(K0[d], u0h[15-d], y0);
        ysh[t] = gelu_f(y0);
        __syncthreads();                               // (A) ysh ready
        // ---- GEMM0: za = col t, zb = col t+1024 over ysh ----
        float a0=0,a1=0,a2=0,a3=0, c0=0,c1=0,c2=0,c3=0;
        for (int k=0;k<H;k+=4){
            float yk0 = ysh[k], yk1 = ysh[k+1], yk2 = ysh[k+2], yk3 = ysh[k+3];
            const float* w = W0 + (size_t)k*H2;
            a0 = fmaf(yk0, w[0],        a0);  c0 = fmaf(yk0, w[H],        c0);
            a1 = fmaf(yk1, w[H2],       a1);  c1 = fmaf(yk1, w[H2+H],     c1);
            a2 = fmaf(yk2, w[2*H2],     a2);  c2 = fmaf(yk2, w[2*H2+H],   c2);
            a3 = fmaf(yk3, w[3*H2],     a3);  c3 = fmaf(yk3, w[3*H2+H],   c3);
        }
        float za = (a0+a1)+(a2+a3) + ba0;
        float zb = (c0+c1)+(c2+c3) + bb0;
        float x = za * sigm_f(zb);
        x = (step==0) ? x + bit : 2.f*x;               // res = u0 (bit, =0 @step0) or y
        // ---- LN0 ----
        float s = x, q = x*x;
        #pragma unroll
        for (int m=32;m>=1;m>>=1){ s += __shfl_xor(s,m,64); q += __shfl_xor(q,m,64); }
        if (lane==0){ red[wv]=s; red[16+wv]=q; }
        __syncthreads();                               // (B)
        float S=0.f, Q=0.f;
        #pragma unroll
        for (int i=0;i<16;i++){ S += red[i]; Q += red[16+i]; }
        float mean = S*(1.f/H), var = Q*(1.f/H) - mean*mean;
        float rstd = rsqrtf(var + 1e-5f);
        float dec_h = (x-mean)*rstd*g0 + be0;
        // ---- layer 1: 16-tap conv y1 (u1 = dec_h history, per-thread) ----
        #pragma unroll
        for (int j=0;j<15;j++) u1h[j] = u1h[j+1];
        u1h[15] = dec_h;
        float y1 = dv1 * dec_h;
        #pragma unroll
        for (int d=0; d<16; d++) y1 = fmaf(K1[d], u1h[15-d], y1);
        ysh[t] = gelu_f(y1);
        __syncthreads();                               // (C) ysh(L1) ready, red free
        // ---- GEMM1 ----
        a0=0;a1=0;a2=0;a3=0; c0=0;c1=0;c2=0;c3=0;
        for (int k=0;k<H;k+=4){
            float yk0 = ysh[k], yk1 = ysh[k+1], yk2 = ysh[k+2], yk3 = ysh[k+3];
            const float* w = W1 + (size_t)k*H2;
            a0 = fmaf(yk0, w[0],        a0);  c0 = fmaf(yk0, w[H],        c0);
            a1 = fmaf(yk1, w[H2],       a1);  c1 = fmaf(yk1, w[H2+H],     c1);
            a2 = fmaf(yk2, w[2*H2],     a2);  c2 = fmaf(yk2, w[2*H2+H],   c2);
            a3 = fmaf(yk3, w[3*H2],     a3);  c3 = fmaf(yk3, w[3*H2+H],   c3);
        }
        za = (a0+a1)+(a2+a3) + ba1;
        zb = (c0+c1)+(c2+c3) + bb1;
        x = za * sigm_f(zb);
        x = (step==0) ? x + bit : 2.f*x;
        // ---- LN1 ----
        s = x; q = x*x;
        #pragma unroll
        for (int m=32;m>=1;m>>=1){ s += __shfl_xor(s,m,64); q += __shfl_xor(q,m,64); }
        if (lane==0){ red[wv]=s; red[16+wv]=q; }
        __syncthreads();                               // (D)
        S=0.f; Q=0.f;
        #pragma unroll
        for (int i=0;i<16;i++){ S += red[i]; Q += red[16+i]; }
        mean = S*(1.f/H); var = Q*(1.f/H) - mean*mean;
        rstd = rsqrtf(var + 1e-5f);
        float d1 = (x-mean)*rstd*g1 + be1 + cv;        // + context
        // ---- head: hs = sum(d1 * headw) ----
        float hp = d1 * hw;
        #pragma unroll
        for (int m=32;m>=1;m>>=1) hp += __shfl_xor(hp,m,64);
        __syncthreads();                               // (E) red free
        if (lane==0) red[wv] = hp;
        __syncthreads();                               // (F)
        float hs = 0.f;
        #pragma unroll
        for (int i=0;i<16;i++) hs += red[i];
        bit = sigm_f(hs + hb);
        if (t==0) out[b*NSTEPS + step] = bit;
        __syncthreads();                               // red/ysh free for next step
    }
}

extern "C" void kernel_launch(void* const* d_in, const int* in_sizes, int n_in,
                              void* d_out, int out_size, void* d_ws, size_t ws_size,
                              hipStream_t stream) {
    const float* in_seq = (const float*)d_in[0];
    const float* inw  = (const float*)d_in[2];
    const float* inb  = (const float*)d_in[3];
    const float* log_dt = (const float*)d_in[4];
    const float* Are = (const float*)d_in[5];
    const float* Aim = (const float*)d_in[6];
    const float* Bre = (const float*)d_in[7];
    const float* Bim = (const float*)d_in[8];
    const float* Cre = (const float*)d_in[9];
    const float* Cim = (const float*)d_in[10];
    const float* Dv  = (const float*)d_in[11];
    const float* outw = (const float*)d_in[12];
    const float* outb = (const float*)d_in[13];
    const float* lng = (const float*)d_in[14];
    const float* lnb = (const float*)d_in[15];
    const float* headw = (const float*)d_in[16];
    const float* headb = (const float*)d_in[17];
    float* out = (float*)d_out;

    float* ws = (float*)d_ws;
    size_t off = 0;
    auto alloc = [&](size_t n){ float* p = ws + off; off += n; return p; };
    float* dAr = alloc((size_t)LAYN*H*NST);
    float* dAi = alloc((size_t)LAYN*H*NST);
    float* dBr = alloc((size_t)LAYN*H*NST);
    float* dBi = alloc((size_t)LAYN*H*NST);
    float* Kbuf = alloc((size_t)LAYN*H*TLEN);
    float* bufA = alloc((size_t)BSZ*TLEN*H);                              // 67MB
    float* bufB = alloc((size_t)BSZ*TLEN*H);                              // 67MB
    __hip_bfloat16* gbf = (__hip_bfloat16*)alloc((size_t)BSZ*TLEN*H/2);   // 33.5MB
    __hip_bfloat16* Abf = (__hip_bfloat16*)alloc((size_t)BSZ*TLEN*H/2);   // 33.5MB
    __hip_bfloat16* Wt  = (__hip_bfloat16*)alloc((size_t)LAYN*H*H2/2);    // 8.4MB
    float* ctx = alloc((size_t)BSZ*H);
    // total ~216 MB (round-3's proven 241.7 MB OK; round-4's 283.6 MB crashed)

    k_precompute<<<(LAYN*H*NST+255)/256, 256, 0, stream>>>(log_dt,Are,Aim,Bre,Bim,dAr,dAi,dBr,dBi);
    k_genK<<<LAYN*H, 64, 0, stream>>>(dAr,dAi,dBr,dBi,Cre,Cim,Kbuf);
    k_wtr<<<dim3(H2/32, H/32, LAYN), 256, 0, stream>>>(outw, Wt);
    k_inproj_x <<<(BSZ*TLEN*H)/256, 256, 0, stream>>>(in_seq, inw, inb, bufA);
    k_inproj_xT<<<(BSZ*TLEN*H)/256, 256, 0, stream>>>(in_seq, inw, inb, bufB);

    // ---- layer 0: res = bufA (b,t,h); xT = bufB (b,h,t)
    k_conv<<<dim3(TLEN/CTT, H), 256, 0, stream>>>(bufB, Kbuf, Dv, gbf, 0);
    k_trcast_bf<<<dim3(TLEN/32, H/32, BSZ), 256, 0, stream>>>(gbf, Abf);
    k_gemm_glu_mfma<<<dim3(BSZ*TLEN/128, H/64), 256, 0, stream>>>(Abf, Wt, outb, bufB);
    k_ln<<<BSZ*TLEN, 256, 0, stream>>>(bufB, bufA, lng, lnb, bufA);
    k_transpose<<<dim3(16,32,32), 256, 0, stream>>>(bufA, bufB);

    // ---- layer 1
    k_conv<<<dim3(TLEN/CTT, H), 256, 0, stream>>>(bufB, Kbuf, Dv, gbf, 1);
    k_trcast_bf<<<dim3(TLEN/32, H/32, BSZ), 256, 0, stream>>>(gbf, Abf);
    k_gemm_glu_mfma<<<dim3(BSZ*TLEN/128, H/64), 256, 0, stream>>>(Abf, Wt + (size_t)H*H2, outb + H2, bufB);
    k_ln<<<BSZ*TLEN, 256, 0, stream>>>(bufB, bufA, lng+H, lnb+H, bufA);

    k_ctx<<<(BSZ*H)/256, 256, 0, stream>>>(bufA, ctx);

    // ---- decode: 32 independent batch-blocks, zero global synchronization
    k_decode<<<BSZ, 1024, 0, stream>>>(Kbuf, Dv, outw, outb, lng, lnb,
                                       ctx, headw, headb, out);
}

// Round 12
// 2397.312 us; speedup vs baseline: 2.4105x; 2.4105x over previous
//
#include <hip/hip_runtime.h>
#include <hip/hip_bf16.h>
#include <math.h>

#define H    1024
#define NST  64
#define LAYN 2
#define BSZ  32
#define TLEN 512
#define NSTEPS 16
#define H2   2048
#define DECBLK 256
#define FLAGSTRIDE 32

typedef __attribute__((ext_vector_type(8))) short bf16x8;
typedef __attribute__((ext_vector_type(4))) float f32x4;

__device__ __forceinline__ float gelu_f(float x){
    return 0.5f*x*(1.0f+erff(x*0.7071067811865475f));
}
__device__ __forceinline__ float sigm_f(float x){
    return 1.0f/(1.0f+expf(-x));
}
__device__ __forceinline__ short bfbits(float x){
    __hip_bfloat16 h = __float2bfloat16(x);
    return *(short*)&h;
}
__device__ __forceinline__ float bf2f(short s){
    unsigned int u = ((unsigned int)(unsigned short)s) << 16;
    return __uint_as_float(u);
}
__device__ __forceinline__ void gload16(const void* g, void* l){
    __builtin_amdgcn_global_load_lds((const __attribute__((address_space(1))) void*)g,
                                     (__attribute__((address_space(3))) void*)l, 16, 0, 0);
}
// relaxed agent-scope (sc1) data path: write-through stores, L2-bypass loads
__device__ __forceinline__ void ast(float* p, float v){
    __hip_atomic_store(p, v, __ATOMIC_RELAXED, __HIP_MEMORY_SCOPE_AGENT);
}
__device__ __forceinline__ float ald(const float* p){
    return __hip_atomic_load(p, __ATOMIC_RELAXED, __HIP_MEMORY_SCOPE_AGENT);
}

// ---------------- discretized SSM params ----------------
__global__ void k_precompute(const float* __restrict__ log_dt,
                             const float* __restrict__ Are, const float* __restrict__ Aim,
                             const float* __restrict__ Bre, const float* __restrict__ Bim,
                             float* __restrict__ dAr, float* __restrict__ dAi,
                             float* __restrict__ dBr, float* __restrict__ dBi){
    int i = blockIdx.x*256 + threadIdx.x;
    if (i >= LAYN*H*NST) return;
    int lh = i / NST;
    float dt = expf(log_dt[lh]);
    float ar = Are[i], ai = Aim[i];
    float e  = expf(dt*ar);
    float sa, ca; sincosf(dt*ai, &sa, &ca);
    float dar = e*ca, dai = e*sa;
    float zr = dar-1.0f, zi = dai;
    float inv = 1.0f/(ar*ar + ai*ai);
    float wr = (zr*ar + zi*ai)*inv;
    float wi = (zi*ar - zr*ai)*inv;
    float br = Bre[i], bi = Bim[i];
    dAr[i]=dar; dAi[i]=dai;
    dBr[i]=wr*br - wi*bi;
    dBi[i]=wr*bi + wi*br;
}

// ---------------- in_proj ----------------
__global__ void k_inproj_x(const float* __restrict__ in, const float* __restrict__ w,
                           const float* __restrict__ bias, float* __restrict__ x){
    int i = blockIdx.x*256+threadIdx.x;          // b*T*H + t*H + h
    int h = i & (H-1);
    int bt = i >> 10;
    x[i] = in[bt]*w[h] + bias[h];
}
__global__ void k_inproj_xT(const float* __restrict__ in, const float* __restrict__ w,
                            const float* __restrict__ bias, float* __restrict__ xT){
    int i = blockIdx.x*256+threadIdx.x;          // b*H*T + h*T + t
    int t = i & (TLEN-1);
    int bh = i >> 9;
    int h = bh & (H-1);
    int b = bh >> 10;
    xT[i] = in[b*TLEN + t]*w[h] + bias[h];
}

// ---------------- S4 conv kernel gen ----------------
__global__ __launch_bounds__(64) void k_genK(
        const float* __restrict__ dAr, const float* __restrict__ dAi,
        const float* __restrict__ dBr, const float* __restrict__ dBi,
        const float* __restrict__ Cre, const float* __restrict__ Cim,
        float* __restrict__ Kbuf){
    __shared__ float trans[16][65];
    int lh = blockIdx.x;
    int lane = threadIdx.x;
    int pi = lh*NST + lane;
    float ar=dAr[pi], ai=dAi[pi];
    float br=dBr[pi], bi=dBi[pi];
    float cr=2.f*Cre[pi], ci=2.f*Cim[pi];
    float wr = cr*br - ci*bi;
    float wi = cr*bi + ci*br;
    float* Krow = Kbuf + (size_t)lh*TLEN;
    int r = lane>>2, q = lane&3;
    for (int c=0;c<TLEN/16;c++){
        #pragma unroll
        for (int i=0;i<16;i++){
            trans[i][lane] = wr;
            float nr = fmaf(wr,ar, -wi*ai);
            float ni = fmaf(wr,ai,  wi*ar);
            wr=nr; wi=ni;
        }
        __syncthreads();
        float s = 0.f;
        #pragma unroll
        for (int m=0;m<16;m++) s += trans[r][q*16+m];
        s += __shfl_xor(s,1,64);
        s += __shfl_xor(s,2,64);
        if (q==0) Krow[c*16 + r] = s;
        __syncthreads();
    }
}

// ---------------- causal Toeplitz conv + D*u + gelu; bf16 (B,H,T) out ----------------
#define CTT 256
#define CJT 64
__global__ __launch_bounds__(256) void k_conv(
        const float* __restrict__ u,            // (B,H,T) f32
        const float* __restrict__ Kbuf,         // (L,H,T)
        const float* __restrict__ Dv,
        __hip_bfloat16* __restrict__ g,         // (B,H,T) bf16
        int layer){
    __shared__ float u_s[CJT][33];
    __shared__ float Ks[CTT+CJT];
    int h  = blockIdx.y;
    int t0 = blockIdx.x * CTT;
    int tid = threadIdx.x;
    int bg = tid & 7;
    int tg = tid >> 3;
    const float* Krow = Kbuf + ((size_t)layer*H + h)*TLEN;
    float acc[8][4];
    #pragma unroll
    for (int i=0;i<8;i++){
        #pragma unroll
        for (int b=0;b<4;b++) acc[i][b]=0.f;
    }
    int ntile = t0/CJT + CTT/CJT;
    for (int jt=0; jt<ntile; jt++){
        int j0 = jt*CJT;
        __syncthreads();
        for (int i=tid; i<CTT+CJT; i+=256){
            int d = t0 - j0 - (CJT-1) + i;
            Ks[i] = (d>=0) ? Krow[d] : 0.f;
        }
        {
            int jj = tid & 63, bq = tid >> 6;
            #pragma unroll
            for (int p=0;p<8;p++){
                int b = bq + p*4;
                u_s[jj][b] = u[((size_t)b*H + h)*TLEN + j0 + jj];
            }
        }
        __syncthreads();
        #pragma unroll 8
        for (int j=0;j<CJT;j++){
            float4 ub = *(const float4*)&u_s[j][bg*4];
            int base = tg*8 + (CJT-1) - j;
            float kv[8];
            #pragma unroll
            for (int i=0;i<8;i++) kv[i] = Ks[base+i];
            #pragma unroll
            for (int i=0;i<8;i++){
                acc[i][0] = fmaf(kv[i], ub.x, acc[i][0]);
                acc[i][1] = fmaf(kv[i], ub.y, acc[i][1]);
                acc[i][2] = fmaf(kv[i], ub.z, acc[i][2]);
                acc[i][3] = fmaf(kv[i], ub.w, acc[i][3]);
            }
        }
    }
    float dv = Dv[layer*H + h];
    int tb = t0 + tg*8;
    #pragma unroll
    for (int b=0;b<4;b++){
        int bb = bg*4 + b;
        const float* urow = u + ((size_t)bb*H + h)*TLEN + tb;
        float4 u0 = *(const float4*)urow;
        float4 u1 = *(const float4*)(urow+4);
        bf16x8 o;
        o[0] = bfbits(gelu_f(fmaf(dv,u0.x, acc[0][b])));
        o[1] = bfbits(gelu_f(fmaf(dv,u0.y, acc[1][b])));
        o[2] = bfbits(gelu_f(fmaf(dv,u0.z, acc[2][b])));
        o[3] = bfbits(gelu_f(fmaf(dv,u0.w, acc[3][b])));
        o[4] = bfbits(gelu_f(fmaf(dv,u1.x, acc[4][b])));
        o[5] = bfbits(gelu_f(fmaf(dv,u1.y, acc[5][b])));
        o[6] = bfbits(gelu_f(fmaf(dv,u1.z, acc[6][b])));
        o[7] = bfbits(gelu_f(fmaf(dv,u1.w, acc[7][b])));
        *(bf16x8*)(g + ((size_t)bb*H + h)*TLEN + tb) = o;
    }
}

// ---------------- bf16 transpose (B,H,T) -> (B,T,H) ----------------
__global__ __launch_bounds__(256) void k_trcast_bf(const __hip_bfloat16* __restrict__ x,
                                                   __hip_bfloat16* __restrict__ y){
    __shared__ __hip_bfloat16 tile[32][34];
    int t0 = blockIdx.x*32, h0 = blockIdx.y*32, b = blockIdx.z;
    int tx = threadIdx.x & 31, ty = threadIdx.x >> 5;
    #pragma unroll
    for (int i=0;i<32;i+=8)
        tile[ty+i][tx] = x[((size_t)(b*H + h0+ty+i))*TLEN + t0+tx];
    __syncthreads();
    #pragma unroll
    for (int i=0;i<32;i+=8)
        y[((size_t)(b*TLEN + t0+ty+i))*H + h0+tx] = tile[tx][ty+i];
}

// ---------------- transpose (b,t,h) -> (b,h,t) f32 ----------------
__global__ __launch_bounds__(256) void k_transpose(const float* __restrict__ x, float* __restrict__ xT){
    __shared__ float tile[32][33];
    int t0 = blockIdx.x*32, h0 = blockIdx.y*32, b = blockIdx.z;
    int tx = threadIdx.x & 31, ty = threadIdx.x >> 5;
    #pragma unroll
    for (int i=0;i<32;i+=8)
        tile[ty+i][tx] = x[((size_t)(b*TLEN + t0+ty+i))*H + h0+tx];
    __syncthreads();
    #pragma unroll
    for (int i=0;i<32;i+=8)
        xT[((size_t)(b*H + h0+ty+i))*TLEN + t0+tx] = tile[tx][ty+i];
}

// ---------------- W (L,H,2H) f32 -> Wt (L,2H,H) bf16 ----------------
__global__ __launch_bounds__(256) void k_wtr(const float* __restrict__ W,
                                             __hip_bfloat16* __restrict__ Wt){
    __shared__ float tile[32][33];
    int n0 = blockIdx.x*32, k0 = blockIdx.y*32, l = blockIdx.z;
    const float* Wl = W + (size_t)l*H*H2;
    __hip_bfloat16* Wtl = Wt + (size_t)l*H*H2;
    int tx = threadIdx.x & 31, ty = threadIdx.x >> 5;
    #pragma unroll
    for (int i=0;i<32;i+=8)
        tile[ty+i][tx] = Wl[(size_t)(k0+ty+i)*H2 + n0+tx];
    __syncthreads();
    #pragma unroll
    for (int i=0;i<32;i+=8)
        Wtl[(size_t)(n0+ty+i)*H + k0+tx] = __float2bfloat16(tile[tx][ty+i]);
}

// ---------------- bf16 MFMA GEMM + bias + GLU fused (encoder) ----------------
__global__ __launch_bounds__(256) void k_gemm_glu_mfma(
        const __hip_bfloat16* __restrict__ Abf,
        const __hip_bfloat16* __restrict__ Wt,
        const float* __restrict__ bias2,         // (2048,)
        float* __restrict__ glu){                // (M,1024)
    __shared__ alignas(16) short As[128*32];
    __shared__ alignas(16) short Bs[128*32];
    const int K = 1024;
    int tid = threadIdx.x;
    int lane = tid & 63, wid = tid >> 6;
    int m0 = blockIdx.x * 128;
    int nb = blockIdx.y * 64;
    int g0 = tid, g1 = tid + 256;
    int r0 = g0 >> 2, r1 = g1 >> 2;
    int wtr0 = nb + ((r0>>6)<<5) + (r0&31) + ((r0>>5)&1)*1024;
    int wtr1 = nb + ((r1>>6)<<5) + (r1&31) + ((r1>>5)&1)*1024;
    const short* Ap = (const short*)Abf;
    const short* Bp = (const short*)Wt;
    const short* Ag0 = Ap + (size_t)(m0 + r0)*K + (g0&3)*8;
    const short* Ag1 = Ap + (size_t)(m0 + r1)*K + (g1&3)*8;
    const short* Bg0 = Bp + (size_t)wtr0*K + (g0&3)*8;
    const short* Bg1 = Bp + (size_t)wtr1*K + (g1&3)*8;
    char* AsB = (char*)As;
    char* BsB = (char*)Bs;
    int wr = wid >> 1, wc = wid & 1;
    int mo = wr*64, no = wc*64;
    f32x4 acc[4][4] = {};
    int arow = (lane & 15)*32 + (lane>>4)*8;
    for (int k0 = 0; k0 < K; k0 += 32){
        gload16(Ag0 + k0, AsB + wid*1024);
        gload16(Ag1 + k0, AsB + 4096 + wid*1024);
        gload16(Bg0 + k0, BsB + wid*1024);
        gload16(Bg1 + k0, BsB + 4096 + wid*1024);
        asm volatile("s_waitcnt vmcnt(0)" ::: "memory");
        __syncthreads();
        bf16x8 a[4], b[4];
        #pragma unroll
        for (int mi=0;mi<4;mi++)
            a[mi] = *(const bf16x8*)(As + (mo + mi*16)*32 + arow);
        #pragma unroll
        for (int ni=0;ni<4;ni++)
            b[ni] = *(const bf16x8*)(Bs + (no + ni*16)*32 + arow);
        #pragma unroll
        for (int mi=0;mi<4;mi++){
            #pragma unroll
            for (int ni=0;ni<4;ni++){
                acc[mi][ni] = __builtin_amdgcn_mfma_f32_16x16x32_bf16(a[mi], b[ni], acc[mi][ni], 0, 0, 0);
            }
        }
        __syncthreads();
    }
    int cbase = nb + wc*32 + (lane&15);
    #pragma unroll
    for (int ni=0;ni<2;ni++){
        int c = cbase + ni*16;
        float ba = bias2[c], bb = bias2[c+1024];
        #pragma unroll
        for (int mi=0;mi<4;mi++){
            #pragma unroll
            for (int r=0;r<4;r++){
                size_t m = m0 + mo + mi*16 + (lane>>4)*4 + r;
                float za = acc[mi][ni][r] + ba;
                float zb = acc[mi][ni+2][r] + bb;
                glu[m*H + c] = za * sigm_f(zb);
            }
        }
    }
}

// ---------------- LayerNorm over H per (b,t) row (encoder) ----------------
__global__ __launch_bounds__(256) void k_ln(const float* __restrict__ glu, const float* __restrict__ res,
        const float* __restrict__ gamma, const float* __restrict__ beta, float* __restrict__ outx){
    __shared__ float red[8];
    int row = blockIdx.x;
    int tid = threadIdx.x;
    float4 gv = *(const float4*)(glu + (size_t)row*H + tid*4);
    float4 rv = *(const float4*)(res + (size_t)row*H + tid*4);
    float x0=gv.x+rv.x, x1=gv.y+rv.y, x2=gv.z+rv.z, x3=gv.w+rv.w;
    float s = x0+x1+x2+x3;
    float q = x0*x0+x1*x1+x2*x2+x3*x3;
    #pragma unroll
    for (int m=32;m>=1;m>>=1){ s += __shfl_xor(s,m,64); q += __shfl_xor(q,m,64); }
    int wv = tid>>6;
    if ((tid&63)==0){ red[wv]=s; red[4+wv]=q; }
    __syncthreads();
    s = red[0]+red[1]+red[2]+red[3];
    q = red[4]+red[5]+red[6]+red[7];
    float m = s*(1.0f/H);
    float v = q*(1.0f/H) - m*m;
    float rstd = rsqrtf(v + 1e-5f);
    float4 gm = *(const float4*)(gamma + tid*4);
    float4 bt = *(const float4*)(beta + tid*4);
    float4 o;
    o.x = (x0-m)*rstd*gm.x + bt.x;
    o.y = (x1-m)*rstd*gm.y + bt.y;
    o.z = (x2-m)*rstd*gm.z + bt.z;
    o.w = (x3-m)*rstd*gm.w + bt.w;
    *(float4*)(outx + (size_t)row*H + tid*4) = o;
}

__global__ void k_ctx(const float* __restrict__ x, float* __restrict__ ctx){
    int i = blockIdx.x*256+threadIdx.x;
    int b = i>>10, h = i&(H-1);
    ctx[i] = x[((size_t)(b*TLEN + TLEN-1))*H + h];
}

// ======================= PERSISTENT DECODE (fence-free) =======================
// All cross-block data via relaxed agent atomics (sc1: write-through, L2-bypass).
// Ordering: __syncthreads drains vmcnt per wave; tid0 then stores relaxed flag.
// Barrier: all-poll-all (thread i polls flag i). No release/acquire fences.
__device__ __forceinline__ void gbar(int* flags, int g, int blk, int tid){
    __syncthreads();   // compiler emits s_waitcnt vmcnt(0) before s_barrier -> stores drained
    if (tid == 0)
        __hip_atomic_store(&flags[blk*FLAGSTRIDE], g, __ATOMIC_RELAXED,
                           __HIP_MEMORY_SCOPE_AGENT);
    int it = 0;
    while (__hip_atomic_load(&flags[tid*FLAGSTRIDE], __ATOMIC_RELAXED,
                             __HIP_MEMORY_SCOPE_AGENT) < g){
        __builtin_amdgcn_s_sleep(1);
        if (++it > 300000) break;   // escape: broken barrier -> wrong answer, not hang
    }
    __syncthreads();
}

// decode GEMM: blocks 0..127, p = blk*8 + (tid>>5), b = tid&31; W rows bf16.
__device__ __forceinline__ void dec_gemm_p(int blk, int tid, float (*u_s)[261],
        const float* __restrict__ ygel, const __hip_bfloat16* __restrict__ Wt,
        const float* __restrict__ b2, float* __restrict__ glud){
    int p = blk*8 + (tid>>5);
    int b = tid & 31;
    const short* wa = (const short*)Wt + (size_t)p*H;
    const short* wb = (const short*)Wt + (size_t)(p+1024)*H;
    float aa=0.f, ab=0.f;
    for (int kq=0; kq<4; kq++){
        __syncthreads();
        #pragma unroll
        for (int i=0;i<32;i++){
            int j = i*256 + tid;
            int row = j >> 8, col = j & 255;
            u_s[row][col] = ald(&ygel[row*H + kq*256 + col]);
        }
        __syncthreads();
        const short* wak = wa + kq*256;
        const short* wbk = wb + kq*256;
        #pragma unroll 4
        for (int k=0;k<256;k+=8){
            bf16x8 wva = *(const bf16x8*)(wak + k);
            bf16x8 wvb = *(const bf16x8*)(wbk + k);
            #pragma unroll
            for (int j=0;j<8;j++){
                float u = u_s[b][k+j];
                aa = fmaf(u, bf2f(wva[j]), aa);
                ab = fmaf(u, bf2f(wvb[j]), ab);
            }
        }
    }
    ast(&glud[b*H + p], (aa + b2[p]) * sigm_f(ab + b2[p+H]));
}

__device__ __forceinline__ void dec_ln_phase(int b, int tid, float* red,
        const float* __restrict__ glud, const float* __restrict__ gamma,
        const float* __restrict__ beta, float* __restrict__ decout,
        const float* __restrict__ ctx, const float* __restrict__ headw,
        const float* __restrict__ headb, float* __restrict__ bits,
        float* __restrict__ out, int step, int last){
    float x0 = ald(&glud[(size_t)b*H + tid*4 + 0]);
    float x1 = ald(&glud[(size_t)b*H + tid*4 + 1]);
    float x2 = ald(&glud[(size_t)b*H + tid*4 + 2]);
    float x3 = ald(&glud[(size_t)b*H + tid*4 + 3]);
    if (step==0){ /* res = u0 = 0 */ }
    else        { x0*=2.f; x1*=2.f; x2*=2.f; x3*=2.f; }   // res = y
    float s = x0+x1+x2+x3, q = x0*x0+x1*x1+x2*x2+x3*x3;
    #pragma unroll
    for (int m=32;m>=1;m>>=1){ s+=__shfl_xor(s,m,64); q+=__shfl_xor(q,m,64); }
    int wv = tid>>6;
    if ((tid&63)==0){ red[wv]=s; red[4+wv]=q; }
    __syncthreads();
    s = red[0]+red[1]+red[2]+red[3];
    q = red[4]+red[5]+red[6]+red[7];
    float m = s*(1.f/H), v = q*(1.f/H)-m*m, rstd = rsqrtf(v+1e-5f);
    float4 gm = *(const float4*)(gamma + tid*4);
    float4 bt = *(const float4*)(beta + tid*4);
    float d0 = (x0-m)*rstd*gm.x+bt.x;
    float d1 = (x1-m)*rstd*gm.y+bt.y;
    float d2 = (x2-m)*rstd*gm.z+bt.z;
    float d3 = (x3-m)*rstd*gm.w+bt.w;
    if (!last){
        ast(&decout[(size_t)b*H + tid*4 + 0], d0);
        ast(&decout[(size_t)b*H + tid*4 + 1], d1);
        ast(&decout[(size_t)b*H + tid*4 + 2], d2);
        ast(&decout[(size_t)b*H + tid*4 + 3], d3);
    } else {
        float4 cv = *(const float4*)(ctx + (size_t)b*H + tid*4);
        d0+=cv.x; d1+=cv.y; d2+=cv.z; d3+=cv.w;
        float4 hw = *(const float4*)(headw + tid*4);
        float hp = d0*hw.x + d1*hw.y + d2*hw.z + d3*hw.w;
        #pragma unroll
        for (int mm=32;mm>=1;mm>>=1) hp += __shfl_xor(hp,mm,64);
        __syncthreads();
        if ((tid&63)==0) red[wv]=hp;
        __syncthreads();
        if (tid==0){
            float hs = red[0]+red[1]+red[2]+red[3] + headb[0];
            float bit = sigm_f(hs);
            ast(&bits[b], bit);
            out[b*NSTEPS + step] = bit;
        }
    }
}

__global__ __launch_bounds__(256, 1) void k_decode(
        const float* __restrict__ dAr, const float* __restrict__ dAi,
        const float* __restrict__ dBr, const float* __restrict__ dBi,
        const float* __restrict__ Cre, const float* __restrict__ Cim,
        const float* __restrict__ Dv,
        const __hip_bfloat16* __restrict__ Wt, const float* __restrict__ bias2,
        const float* __restrict__ lng, const float* __restrict__ lnb,
        const float* __restrict__ ctx, const float* __restrict__ headw,
        const float* __restrict__ headb,
        float* __restrict__ ygel, float* __restrict__ glud,
        float* __restrict__ dec, float* __restrict__ bits,
        float* __restrict__ out, int* __restrict__ flags){
    __shared__ float u_s[32][261];
    __shared__ float scr[4][32][66];
    __shared__ float red[8];
    int blk = blockIdx.x, tid = threadIdx.x;
    int wv = tid >> 6, lane = tid & 63;
    int h = blk*4 + wv;                  // wave owns h; lane owns n=lane
    int p0 = h*NST + lane, p1 = (H+h)*NST + lane;
    float ar0=dAr[p0], ai0=dAi[p0], br0=dBr[p0], bi0=dBi[p0];
    float cr0=Cre[p0], ci0=Cim[p0];
    float ar1=dAr[p1], ai1=dAi[p1], br1=dBr[p1], bi1=dBi[p1];
    float cr1=Cre[p1], ci1=Cim[p1];
    float dv0 = Dv[h], dv1 = Dv[H+h];
    float s0r[32], s0i[32], s1r[32], s1i[32];
    #pragma unroll
    for (int j=0;j<32;j++){ s0r[j]=0.f; s0i[j]=0.f; s1r[j]=0.f; s1i[j]=0.f; }
    int g = 1;
    for (int step=0; step<NSTEPS; step++){
        // ---- layer 0 state: lane owns (h, n=lane, all 32 b)
        {
            float uvec = (step==0) ? 0.f : ald(&bits[lane & 31]);
            #pragma unroll
            for (int b=0;b<32;b++){
                float ub = __shfl(uvec, b, 64);
                float nr = fmaf(ar0,s0r[b], fmaf(-ai0,s0i[b], br0*ub));
                float ni = fmaf(ai0,s0r[b], fmaf( ar0,s0i[b], bi0*ub));
                s0r[b]=nr; s0i[b]=ni;
                scr[wv][b][lane] = fmaf(cr0, nr, -ci0*ni);
            }
            __syncthreads();
            int b = lane & 31, half = lane >> 5;
            float s = 0.f;
            #pragma unroll
            for (int j=0;j<32;j++) s += scr[wv][b][half*32 + j];
            s += __shfl_xor(s, 32, 64);
            if (lane < 32) ast(&ygel[b*H + h], gelu_f(fmaf(2.f, s, dv0*uvec)));
            __syncthreads();
        }
        gbar(flags, g++, blk, tid);
        if (blk < 128) dec_gemm_p(blk, tid, u_s, ygel, Wt, bias2, glud);
        gbar(flags, g++, blk, tid);
        if (blk < 32) dec_ln_phase(blk, tid, red, glud, lng, lnb, dec,
                                   ctx, headw, headb, bits, out, step, 0);
        gbar(flags, g++, blk, tid);
        // ---- layer 1 state (u = dec[b*H + h])
        {
            float uvec = ald(&dec[(lane & 31)*H + h]);
            #pragma unroll
            for (int b=0;b<32;b++){
                float ub = __shfl(uvec, b, 64);
                float nr = fmaf(ar1,s1r[b], fmaf(-ai1,s1i[b], br1*ub));
                float ni = fmaf(ai1,s1r[b], fmaf( ar1,s1i[b], bi1*ub));
                s1r[b]=nr; s1i[b]=ni;
                scr[wv][b][lane] = fmaf(cr1, nr, -ci1*ni);
            }
            __syncthreads();
            int b = lane & 31, half = lane >> 5;
            float s = 0.f;
            #pragma unroll
            for (int j=0;j<32;j++) s += scr[wv][b][half*32 + j];
            s += __shfl_xor(s, 32, 64);
            if (lane < 32) ast(&ygel[b*H + h], gelu_f(fmaf(2.f, s, dv1*uvec)));
            __syncthreads();
        }
        gbar(flags, g++, blk, tid);
        if (blk < 128) dec_gemm_p(blk, tid, u_s, ygel, Wt + (size_t)H*H2, bias2 + H2, glud);
        gbar(flags, g++, blk, tid);
        if (blk < 32) dec_ln_phase(blk, tid, red, glud, lng+H, lnb+H, dec,
                                   ctx, headw, headb, bits, out, step, 1);
        if (step < NSTEPS-1)
            gbar(flags, g++, blk, tid);
    }
}

extern "C" void kernel_launch(void* const* d_in, const int* in_sizes, int n_in,
                              void* d_out, int out_size, void* d_ws, size_t ws_size,
                              hipStream_t stream) {
    const float* in_seq = (const float*)d_in[0];
    const float* inw  = (const float*)d_in[2];
    const float* inb  = (const float*)d_in[3];
    const float* log_dt = (const float*)d_in[4];
    const float* Are = (const float*)d_in[5];
    const float* Aim = (const float*)d_in[6];
    const float* Bre = (const float*)d_in[7];
    const float* Bim = (const float*)d_in[8];
    const float* Cre = (const float*)d_in[9];
    const float* Cim = (const float*)d_in[10];
    const float* Dv  = (const float*)d_in[11];
    const float* outw = (const float*)d_in[12];
    const float* outb = (const float*)d_in[13];
    const float* lng = (const float*)d_in[14];
    const float* lnb = (const float*)d_in[15];
    const float* headw = (const float*)d_in[16];
    const float* headb = (const float*)d_in[17];
    float* out = (float*)d_out;

    float* ws = (float*)d_ws;
    size_t off = 0;
    auto alloc = [&](size_t n){ float* p = ws + off; off += n; return p; };
    float* dAr = alloc((size_t)LAYN*H*NST);
    float* dAi = alloc((size_t)LAYN*H*NST);
    float* dBr = alloc((size_t)LAYN*H*NST);
    float* dBi = alloc((size_t)LAYN*H*NST);
    float* Kbuf = alloc((size_t)LAYN*H*TLEN);
    float* bufA = alloc((size_t)BSZ*TLEN*H);                              // 67MB
    float* bufB = alloc((size_t)BSZ*TLEN*H);                              // 67MB
    __hip_bfloat16* gbf = (__hip_bfloat16*)alloc((size_t)BSZ*TLEN*H/2);   // 33.5MB
    __hip_bfloat16* Abf = (__hip_bfloat16*)alloc((size_t)BSZ*TLEN*H/2);   // 33.5MB
    __hip_bfloat16* Wt  = (__hip_bfloat16*)alloc((size_t)LAYN*H*H2/2);    // 8.4MB
    float* ctx = alloc((size_t)BSZ*H);
    float* ygel = alloc((size_t)BSZ*H);
    float* glud = alloc((size_t)BSZ*H);
    float* dec  = alloc((size_t)BSZ*H);
    float* bits = alloc(64);
    int*   flags = (int*)alloc(DECBLK*FLAGSTRIDE);
    // total ~214 MB (round-3's proven 241.7 MB OK; round-4's 283.6 MB crashed)

    k_precompute<<<(LAYN*H*NST+255)/256, 256, 0, stream>>>(log_dt,Are,Aim,Bre,Bim,dAr,dAi,dBr,dBi);
    k_genK<<<LAYN*H, 64, 0, stream>>>(dAr,dAi,dBr,dBi,Cre,Cim,Kbuf);
    k_wtr<<<dim3(H2/32, H/32, LAYN), 256, 0, stream>>>(outw, Wt);
    k_inproj_x <<<(BSZ*TLEN*H)/256, 256, 0, stream>>>(in_seq, inw, inb, bufA);
    k_inproj_xT<<<(BSZ*TLEN*H)/256, 256, 0, stream>>>(in_seq, inw, inb, bufB);

    // ---- layer 0: res = bufA (b,t,h); xT = bufB (b,h,t)
    k_conv<<<dim3(TLEN/CTT, H), 256, 0, stream>>>(bufB, Kbuf, Dv, gbf, 0);
    k_trcast_bf<<<dim3(TLEN/32, H/32, BSZ), 256, 0, stream>>>(gbf, Abf);
    k_gemm_glu_mfma<<<dim3(BSZ*TLEN/128, H/64), 256, 0, stream>>>(Abf, Wt, outb, bufB);
    k_ln<<<BSZ*TLEN, 256, 0, stream>>>(bufB, bufA, lng, lnb, bufA);
    k_transpose<<<dim3(16,32,32), 256, 0, stream>>>(bufA, bufB);

    // ---- layer 1
    k_conv<<<dim3(TLEN/CTT, H), 256, 0, stream>>>(bufB, Kbuf, Dv, gbf, 1);
    k_trcast_bf<<<dim3(TLEN/32, H/32, BSZ), 256, 0, stream>>>(gbf, Abf);
    k_gemm_glu_mfma<<<dim3(BSZ*TLEN/128, H/64), 256, 0, stream>>>(Abf, Wt + (size_t)H*H2, outb + H2, bufB);
    k_ln<<<BSZ*TLEN, 256, 0, stream>>>(bufB, bufA, lng+H, lnb+H, bufA);

    k_ctx<<<(BSZ*H)/256, 256, 0, stream>>>(bufA, ctx);

    // ---- decode: persistent kernel, fence-free generation barriers
    hipMemsetAsync(flags, 0, sizeof(int)*DECBLK*FLAGSTRIDE, stream);
    k_decode<<<DECBLK, 256, 0, stream>>>(dAr,dAi,dBr,dBi,Cre,Cim,Dv,
                                         Wt, outb, lng, lnb, ctx, headw, headb,
                                         ygel, glud, dec, bits, out, flags);
}

// Round 13
// 2066.520 us; speedup vs baseline: 2.7964x; 1.1601x over previous
//
#include <hip/hip_runtime.h>
#include <hip/hip_bf16.h>
#include <math.h>

#define H    1024
#define NST  64
#define LAYN 2
#define BSZ  32
#define TLEN 512
#define NSTEPS 16
#define H2   2048
#define FLAGSTRIDE 32
#define GBLK 8

typedef __attribute__((ext_vector_type(8))) short bf16x8;
typedef __attribute__((ext_vector_type(4))) float f32x4;

__device__ __forceinline__ float gelu_f(float x){
    return 0.5f*x*(1.0f+erff(x*0.7071067811865475f));
}
__device__ __forceinline__ float sigm_f(float x){
    return 1.0f/(1.0f+expf(-x));
}
__device__ __forceinline__ short bfbits(float x){
    __hip_bfloat16 h = __float2bfloat16(x);
    return *(short*)&h;
}
__device__ __forceinline__ float bf2f(short s){
    unsigned int u = ((unsigned int)(unsigned short)s) << 16;
    return __uint_as_float(u);
}
__device__ __forceinline__ void gload16(const void* g, void* l){
    __builtin_amdgcn_global_load_lds((const __attribute__((address_space(1))) void*)g,
                                     (__attribute__((address_space(3))) void*)l, 16, 0, 0);
}
// relaxed agent-scope data path (validated correct round 12)
__device__ __forceinline__ void ast(float* p, float v){
    __hip_atomic_store(p, v, __ATOMIC_RELAXED, __HIP_MEMORY_SCOPE_AGENT);
}
__device__ __forceinline__ float ald(const float* p){
    return __hip_atomic_load(p, __ATOMIC_RELAXED, __HIP_MEMORY_SCOPE_AGENT);
}

// ---------------- discretized SSM params ----------------
__global__ void k_precompute(const float* __restrict__ log_dt,
                             const float* __restrict__ Are, const float* __restrict__ Aim,
                             const float* __restrict__ Bre, const float* __restrict__ Bim,
                             float* __restrict__ dAr, float* __restrict__ dAi,
                             float* __restrict__ dBr, float* __restrict__ dBi){
    int i = blockIdx.x*256 + threadIdx.x;
    if (i >= LAYN*H*NST) return;
    int lh = i / NST;
    float dt = expf(log_dt[lh]);
    float ar = Are[i], ai = Aim[i];
    float e  = expf(dt*ar);
    float sa, ca; sincosf(dt*ai, &sa, &ca);
    float dar = e*ca, dai = e*sa;
    float zr = dar-1.0f, zi = dai;
    float inv = 1.0f/(ar*ar + ai*ai);
    float wr = (zr*ar + zi*ai)*inv;
    float wi = (zi*ar - zr*ai)*inv;
    float br = Bre[i], bi = Bim[i];
    dAr[i]=dar; dAi[i]=dai;
    dBr[i]=wr*br - wi*bi;
    dBi[i]=wr*bi + wi*br;
}

// ---------------- in_proj ----------------
__global__ void k_inproj_x(const float* __restrict__ in, const float* __restrict__ w,
                           const float* __restrict__ bias, float* __restrict__ x){
    int i = blockIdx.x*256+threadIdx.x;          // b*T*H + t*H + h
    int h = i & (H-1);
    int bt = i >> 10;
    x[i] = in[bt]*w[h] + bias[h];
}
__global__ void k_inproj_xT(const float* __restrict__ in, const float* __restrict__ w,
                            const float* __restrict__ bias, float* __restrict__ xT){
    int i = blockIdx.x*256+threadIdx.x;          // b*H*T + h*T + t
    int t = i & (TLEN-1);
    int bh = i >> 9;
    int h = bh & (H-1);
    int b = bh >> 10;
    xT[i] = in[b*TLEN + t]*w[h] + bias[h];
}

// ---------------- S4 conv kernel gen ----------------
__global__ __launch_bounds__(64) void k_genK(
        const float* __restrict__ dAr, const float* __restrict__ dAi,
        const float* __restrict__ dBr, const float* __restrict__ dBi,
        const float* __restrict__ Cre, const float* __restrict__ Cim,
        float* __restrict__ Kbuf){
    __shared__ float trans[16][65];
    int lh = blockIdx.x;
    int lane = threadIdx.x;
    int pi = lh*NST + lane;
    float ar=dAr[pi], ai=dAi[pi];
    float br=dBr[pi], bi=dBi[pi];
    float cr=2.f*Cre[pi], ci=2.f*Cim[pi];
    float wr = cr*br - ci*bi;
    float wi = cr*bi + ci*br;
    float* Krow = Kbuf + (size_t)lh*TLEN;
    int r = lane>>2, q = lane&3;
    for (int c=0;c<TLEN/16;c++){
        #pragma unroll
        for (int i=0;i<16;i++){
            trans[i][lane] = wr;
            float nr = fmaf(wr,ar, -wi*ai);
            float ni = fmaf(wr,ai,  wi*ar);
            wr=nr; wi=ni;
        }
        __syncthreads();
        float s = 0.f;
        #pragma unroll
        for (int m=0;m<16;m++) s += trans[r][q*16+m];
        s += __shfl_xor(s,1,64);
        s += __shfl_xor(s,2,64);
        if (q==0) Krow[c*16 + r] = s;
        __syncthreads();
    }
}

// ---------------- causal Toeplitz conv + D*u + gelu; bf16 (B,H,T) out ----------------
#define CTT 256
#define CJT 64
__global__ __launch_bounds__(256) void k_conv(
        const float* __restrict__ u,            // (B,H,T) f32
        const float* __restrict__ Kbuf,         // (L,H,T)
        const float* __restrict__ Dv,
        __hip_bfloat16* __restrict__ g,         // (B,H,T) bf16
        int layer){
    __shared__ float u_s[CJT][33];
    __shared__ float Ks[CTT+CJT];
    int h  = blockIdx.y;
    int t0 = blockIdx.x * CTT;
    int tid = threadIdx.x;
    int bg = tid & 7;
    int tg = tid >> 3;
    const float* Krow = Kbuf + ((size_t)layer*H + h)*TLEN;
    float acc[8][4];
    #pragma unroll
    for (int i=0;i<8;i++){
        #pragma unroll
        for (int b=0;b<4;b++) acc[i][b]=0.f;
    }
    int ntile = t0/CJT + CTT/CJT;
    for (int jt=0; jt<ntile; jt++){
        int j0 = jt*CJT;
        __syncthreads();
        for (int i=tid; i<CTT+CJT; i+=256){
            int d = t0 - j0 - (CJT-1) + i;
            Ks[i] = (d>=0) ? Krow[d] : 0.f;
        }
        {
            int jj = tid & 63, bq = tid >> 6;
            #pragma unroll
            for (int p=0;p<8;p++){
                int b = bq + p*4;
                u_s[jj][b] = u[((size_t)b*H + h)*TLEN + j0 + jj];
            }
        }
        __syncthreads();
        #pragma unroll 8
        for (int j=0;j<CJT;j++){
            float4 ub = *(const float4*)&u_s[j][bg*4];
            int base = tg*8 + (CJT-1) - j;
            float kv[8];
            #pragma unroll
            for (int i=0;i<8;i++) kv[i] = Ks[base+i];
            #pragma unroll
            for (int i=0;i<8;i++){
                acc[i][0] = fmaf(kv[i], ub.x, acc[i][0]);
                acc[i][1] = fmaf(kv[i], ub.y, acc[i][1]);
                acc[i][2] = fmaf(kv[i], ub.z, acc[i][2]);
                acc[i][3] = fmaf(kv[i], ub.w, acc[i][3]);
            }
        }
    }
    float dv = Dv[layer*H + h];
    int tb = t0 + tg*8;
    #pragma unroll
    for (int b=0;b<4;b++){
        int bb = bg*4 + b;
        const float* urow = u + ((size_t)bb*H + h)*TLEN + tb;
        float4 u0 = *(const float4*)urow;
        float4 u1 = *(const float4*)(urow+4);
        bf16x8 o;
        o[0] = bfbits(gelu_f(fmaf(dv,u0.x, acc[0][b])));
        o[1] = bfbits(gelu_f(fmaf(dv,u0.y, acc[1][b])));
        o[2] = bfbits(gelu_f(fmaf(dv,u0.z, acc[2][b])));
        o[3] = bfbits(gelu_f(fmaf(dv,u0.w, acc[3][b])));
        o[4] = bfbits(gelu_f(fmaf(dv,u1.x, acc[4][b])));
        o[5] = bfbits(gelu_f(fmaf(dv,u1.y, acc[5][b])));
        o[6] = bfbits(gelu_f(fmaf(dv,u1.z, acc[6][b])));
        o[7] = bfbits(gelu_f(fmaf(dv,u1.w, acc[7][b])));
        *(bf16x8*)(g + ((size_t)bb*H + h)*TLEN + tb) = o;
    }
}

// ---------------- bf16 transpose (B,H,T) -> (B,T,H) ----------------
__global__ __launch_bounds__(256) void k_trcast_bf(const __hip_bfloat16* __restrict__ x,
                                                   __hip_bfloat16* __restrict__ y){
    __shared__ __hip_bfloat16 tile[32][34];
    int t0 = blockIdx.x*32, h0 = blockIdx.y*32, b = blockIdx.z;
    int tx = threadIdx.x & 31, ty = threadIdx.x >> 5;
    #pragma unroll
    for (int i=0;i<32;i+=8)
        tile[ty+i][tx] = x[((size_t)(b*H + h0+ty+i))*TLEN + t0+tx];
    __syncthreads();
    #pragma unroll
    for (int i=0;i<32;i+=8)
        y[((size_t)(b*TLEN + t0+ty+i))*H + h0+tx] = tile[tx][ty+i];
}

// ---------------- transpose (b,t,h) -> (b,h,t) f32 ----------------
__global__ __launch_bounds__(256) void k_transpose(const float* __restrict__ x, float* __restrict__ xT){
    __shared__ float tile[32][33];
    int t0 = blockIdx.x*32, h0 = blockIdx.y*32, b = blockIdx.z;
    int tx = threadIdx.x & 31, ty = threadIdx.x >> 5;
    #pragma unroll
    for (int i=0;i<32;i+=8)
        tile[ty+i][tx] = x[((size_t)(b*TLEN + t0+ty+i))*H + h0+tx];
    __syncthreads();
    #pragma unroll
    for (int i=0;i<32;i+=8)
        xT[((size_t)(b*H + h0+ty+i))*TLEN + t0+tx] = tile[tx][ty+i];
}

// ---------------- W (L,H,2H) f32 -> Wt (L,2H,H) bf16 (encoder GEMM B) ----------------
__global__ __launch_bounds__(256) void k_wtr(const float* __restrict__ W,
                                             __hip_bfloat16* __restrict__ Wt){
    __shared__ float tile[32][33];
    int n0 = blockIdx.x*32, k0 = blockIdx.y*32, l = blockIdx.z;
    const float* Wl = W + (size_t)l*H*H2;
    __hip_bfloat16* Wtl = Wt + (size_t)l*H*H2;
    int tx = threadIdx.x & 31, ty = threadIdx.x >> 5;
    #pragma unroll
    for (int i=0;i<32;i+=8)
        tile[ty+i][tx] = Wl[(size_t)(k0+ty+i)*H2 + n0+tx];
    __syncthreads();
    #pragma unroll
    for (int i=0;i<32;i+=8)
        Wtl[(size_t)(n0+ty+i)*H + k0+tx] = __float2bfloat16(tile[tx][ty+i]);
}

// ---------------- W (L,H,2H) f32 -> same-layout bf16 (decode GEMV) ----------------
__global__ void k_wcast(const float* __restrict__ W, __hip_bfloat16* __restrict__ Wo){
    int i = blockIdx.x*256 + threadIdx.x;
    Wo[i] = __float2bfloat16(W[i]);
}

// ---------------- bf16 MFMA GEMM + bias + GLU fused (encoder) ----------------
__global__ __launch_bounds__(256) void k_gemm_glu_mfma(
        const __hip_bfloat16* __restrict__ Abf,
        const __hip_bfloat16* __restrict__ Wt,
        const float* __restrict__ bias2,         // (2048,)
        float* __restrict__ glu){                // (M,1024)
    __shared__ alignas(16) short As[128*32];
    __shared__ alignas(16) short Bs[128*32];
    const int K = 1024;
    int tid = threadIdx.x;
    int lane = tid & 63, wid = tid >> 6;
    int m0 = blockIdx.x * 128;
    int nb = blockIdx.y * 64;
    int g0 = tid, g1 = tid + 256;
    int r0 = g0 >> 2, r1 = g1 >> 2;
    int wtr0 = nb + ((r0>>6)<<5) + (r0&31) + ((r0>>5)&1)*1024;
    int wtr1 = nb + ((r1>>6)<<5) + (r1&31) + ((r1>>5)&1)*1024;
    const short* Ap = (const short*)Abf;
    const short* Bp = (const short*)Wt;
    const short* Ag0 = Ap + (size_t)(m0 + r0)*K + (g0&3)*8;
    const short* Ag1 = Ap + (size_t)(m0 + r1)*K + (g1&3)*8;
    const short* Bg0 = Bp + (size_t)wtr0*K + (g0&3)*8;
    const short* Bg1 = Bp + (size_t)wtr1*K + (g1&3)*8;
    char* AsB = (char*)As;
    char* BsB = (char*)Bs;
    int wr = wid >> 1, wc = wid & 1;
    int mo = wr*64, no = wc*64;
    f32x4 acc[4][4] = {};
    int arow = (lane & 15)*32 + (lane>>4)*8;
    for (int k0 = 0; k0 < K; k0 += 32){
        gload16(Ag0 + k0, AsB + wid*1024);
        gload16(Ag1 + k0, AsB + 4096 + wid*1024);
        gload16(Bg0 + k0, BsB + wid*1024);
        gload16(Bg1 + k0, BsB + 4096 + wid*1024);
        asm volatile("s_waitcnt vmcnt(0)" ::: "memory");
        __syncthreads();
        bf16x8 a[4], b[4];
        #pragma unroll
        for (int mi=0;mi<4;mi++)
            a[mi] = *(const bf16x8*)(As + (mo + mi*16)*32 + arow);
        #pragma unroll
        for (int ni=0;ni<4;ni++)
            b[ni] = *(const bf16x8*)(Bs + (no + ni*16)*32 + arow);
        #pragma unroll
        for (int mi=0;mi<4;mi++){
            #pragma unroll
            for (int ni=0;ni<4;ni++){
                acc[mi][ni] = __builtin_amdgcn_mfma_f32_16x16x32_bf16(a[mi], b[ni], acc[mi][ni], 0, 0, 0);
            }
        }
        __syncthreads();
    }
    int cbase = nb + wc*32 + (lane&15);
    #pragma unroll
    for (int ni=0;ni<2;ni++){
        int c = cbase + ni*16;
        float ba = bias2[c], bb = bias2[c+1024];
        #pragma unroll
        for (int mi=0;mi<4;mi++){
            #pragma unroll
            for (int r=0;r<4;r++){
                size_t m = m0 + mo + mi*16 + (lane>>4)*4 + r;
                float za = acc[mi][ni][r] + ba;
                float zb = acc[mi][ni+2][r] + bb;
                glu[m*H + c] = za * sigm_f(zb);
            }
        }
    }
}

// ---------------- LayerNorm over H per (b,t) row (encoder) ----------------
__global__ __launch_bounds__(256) void k_ln(const float* __restrict__ glu, const float* __restrict__ res,
        const float* __restrict__ gamma, const float* __restrict__ beta, float* __restrict__ outx){
    __shared__ float red[8];
    int row = blockIdx.x;
    int tid = threadIdx.x;
    float4 gv = *(const float4*)(glu + (size_t)row*H + tid*4);
    float4 rv = *(const float4*)(res + (size_t)row*H + tid*4);
    float x0=gv.x+rv.x, x1=gv.y+rv.y, x2=gv.z+rv.z, x3=gv.w+rv.w;
    float s = x0+x1+x2+x3;
    float q = x0*x0+x1*x1+x2*x2+x3*x3;
    #pragma unroll
    for (int m=32;m>=1;m>>=1){ s += __shfl_xor(s,m,64); q += __shfl_xor(q,m,64); }
    int wv = tid>>6;
    if ((tid&63)==0){ red[wv]=s; red[4+wv]=q; }
    __syncthreads();
    s = red[0]+red[1]+red[2]+red[3];
    q = red[4]+red[5]+red[6]+red[7];
    float m = s*(1.0f/H);
    float v = q*(1.0f/H) - m*m;
    float rstd = rsqrtf(v + 1e-5f);
    float4 gm = *(const float4*)(gamma + tid*4);
    float4 bt = *(const float4*)(beta + tid*4);
    float4 o;
    o.x = (x0-m)*rstd*gm.x + bt.x;
    o.y = (x1-m)*rstd*gm.y + bt.y;
    o.z = (x2-m)*rstd*gm.z + bt.z;
    o.w = (x3-m)*rstd*gm.w + bt.w;
    *(float4*)(outx + (size_t)row*H + tid*4) = o;
}

__global__ void k_ctx(const float* __restrict__ x, float* __restrict__ ctx){
    int i = blockIdx.x*256+threadIdx.x;
    int b = i>>10, h = i&(H-1);
    ctx[i] = x[((size_t)(b*TLEN + TLEN-1))*H + h];
}

// ======================= GROUP-LOCAL DECODE =======================
// 32 groups (one per batch) x 8 blocks; group = blocks {b, b+32, ..., b+224}
// -> same XCD under round-robin dispatch, so sync + data stay in one L2.
// Leader (j=0) does vector phases via 16-tap Toeplitz conv (no SSM state);
// all 8 blocks split the 1024 GLU col-pairs for the GEMV phases.
__device__ __forceinline__ void gbar_grp(int* gfl, int g, int tid){
    __syncthreads();   // drains vmcnt per wave before s_barrier -> stores visible-ordered
    if (tid == 0)
        __hip_atomic_store(gfl + (int)(blockIdx.x >> 5)*FLAGSTRIDE, g,
                           __ATOMIC_RELAXED, __HIP_MEMORY_SCOPE_AGENT);
    if (tid < GBLK){
        int it = 0;
        while (__hip_atomic_load(gfl + tid*FLAGSTRIDE, __ATOMIC_RELAXED,
                                 __HIP_MEMORY_SCOPE_AGENT) < g){
            __builtin_amdgcn_s_sleep(1);
            if (++it > 1000000) break;   // escape: wrong answer, not hang
        }
    }
    __syncthreads();
}

__global__ __launch_bounds__(1024, 1) void k_decode(
        const float* __restrict__ Kbuf, const float* __restrict__ Dv,
        const __hip_bfloat16* __restrict__ Wdb, const float* __restrict__ bias2,
        const float* __restrict__ lng, const float* __restrict__ lnb,
        const float* __restrict__ ctx, const float* __restrict__ headw,
        const float* __restrict__ headb,
        float* __restrict__ ygel0, float* __restrict__ ygel1,
        float* __restrict__ glud0, float* __restrict__ glud1,
        float* __restrict__ out, int* __restrict__ flags){
    __shared__ float hist[16][H];        // 64KB: leader's dec history (per-h column)
    __shared__ float ysh[H];             // 4KB
    __shared__ float part[2][8][128];    // 8KB
    __shared__ float red[32];
    __shared__ float bitsh[16];
    int bid = blockIdx.x;
    int b = bid & 31, j = bid >> 5;
    int tid = threadIdx.x;
    int lane = tid & 63, wv = tid >> 6;
    bool leader = (j == 0);
    // per-h step-invariant params (used by leader; harmless elsewhere)
    float K0d[16], K1d[16];
    #pragma unroll
    for (int d=0; d<16; d++){
        K0d[d] = Kbuf[(size_t)tid*TLEN + d];
        K1d[d] = Kbuf[(size_t)(H + tid)*TLEN + d];
    }
    float dv0 = Dv[tid], dv1 = Dv[H+tid];
    float lg0 = lng[tid], be0 = lnb[tid], lg1 = lng[H+tid], be1 = lnb[H+tid];
    float cvx = ctx[b*H + tid], hw = headw[tid], hb = headb[0];
    #pragma unroll
    for (int d=0; d<16; d++) hist[d][tid] = 0.f;
    if (tid < 16) bitsh[tid] = 0.f;
    __syncthreads();
    int pr = tid & 127;                  // pair index within block slice
    int ks = tid >> 7;                   // k-slice 0..7
    int col = (j<<7) + pr;               // global pair col in [0,1024)
    const unsigned short* WB0 = (const unsigned short*)Wdb;
    const unsigned short* WB1 = (const unsigned short*)Wdb + (size_t)H*H2;
    float ba0 = bias2[col], bb0 = bias2[1024 + col];
    float ba1 = bias2[H2 + col], bb1 = bias2[H2 + 1024 + col];
    int* gfl = flags + b*GBLK*FLAGSTRIDE;
    int g = 1;
    for (int s=0; s<NSTEPS; s++){
        // ===== A: leader: LN1+head of prev step -> bit_{s-1}, out; then ygel0 =====
        if (leader){
            if (s > 0){
                float x = ald(&glud1[(size_t)b*H + tid]);
                x = (s-1 == 0) ? x : 2.f*x;          // res = u0(=0) at step0 else y
                float su = x, qu = x*x;
                #pragma unroll
                for (int m=32;m>=1;m>>=1){ su += __shfl_xor(su,m,64); qu += __shfl_xor(qu,m,64); }
                if (lane==0){ red[wv]=su; red[16+wv]=qu; }
                __syncthreads();
                float S=0.f, Q=0.f;
                #pragma unroll
                for (int i=0;i<16;i++){ S += red[i]; Q += red[16+i]; }
                float mean = S*(1.f/H), var = Q*(1.f/H)-mean*mean;
                float rstd = rsqrtf(var + 1e-5f);
                float d1 = (x-mean)*rstd*lg1 + be1 + cvx;
                float hp = d1*hw;
                #pragma unroll
                for (int m=32;m>=1;m>>=1) hp += __shfl_xor(hp,m,64);
                __syncthreads();
                if (lane==0) red[wv] = hp;
                __syncthreads();
                float hs = 0.f;
                #pragma unroll
                for (int i=0;i<16;i++) hs += red[i];
                float bit = sigm_f(hs + hb);
                if (tid==0){ out[b*NSTEPS + (s-1)] = bit; bitsh[(s-1)&15] = bit; }
                __syncthreads();
            }
            // y0[s] = dv0*u0 + sum_d K0[d]*u0[s-d],  u0[sg] = bit_{sg-1}
            float u0 = (s==0) ? 0.f : bitsh[(s-1)&15];
            float y0 = dv0*u0;
            #pragma unroll
            for (int d=0; d<16; d++){
                int idx = s-1-d;
                float uv = (idx >= 0) ? bitsh[idx & 15] : 0.f;
                y0 = fmaf(K0d[d], uv, y0);
            }
            ast(&ygel0[(size_t)b*H + tid], gelu_f(y0));
        }
        gbar_grp(gfl, g++, tid);
        // ===== B: GEMV0 + GLU (all 8 blocks) =====
        ysh[tid] = ald(&ygel0[(size_t)b*H + tid]);
        __syncthreads();
        {
            float za = 0.f, zb = 0.f;
            const unsigned short* base = WB0 + (size_t)(ks*128)*H2 + col;
            #pragma unroll 8
            for (int k=0;k<128;k++){
                float y = ysh[ks*128 + k];
                za = fmaf(y, bf2f((short)base[(size_t)k*H2]),        za);
                zb = fmaf(y, bf2f((short)base[(size_t)k*H2 + 1024]), zb);
            }
            part[0][ks][pr] = za; part[1][ks][pr] = zb;
        }
        __syncthreads();
        if (tid < 128){
            float sa=0.f, sb=0.f;
            #pragma unroll
            for (int q=0;q<8;q++){ sa += part[0][q][tid]; sb += part[1][q][tid]; }
            ast(&glud0[(size_t)b*H + col], (sa + ba0) * sigm_f(sb + bb0));
        }
        gbar_grp(gfl, g++, tid);
        // ===== C: leader: LN0 -> dec; push history; conv K1 -> ygel1 =====
        if (leader){
            float x = ald(&glud0[(size_t)b*H + tid]);
            x = (s == 0) ? x : 2.f*x;
            float su = x, qu = x*x;
            #pragma unroll
            for (int m=32;m>=1;m>>=1){ su += __shfl_xor(su,m,64); qu += __shfl_xor(qu,m,64); }
            if (lane==0){ red[wv]=su; red[16+wv]=qu; }
            __syncthreads();
            float S=0.f, Q=0.f;
            #pragma unroll
            for (int i=0;i<16;i++){ S += red[i]; Q += red[16+i]; }
            float mean = S*(1.f/H), var = Q*(1.f/H)-mean*mean;
            float rstd = rsqrtf(var + 1e-5f);
            float dec_h = (x-mean)*rstd*lg0 + be0;
            hist[s & 15][tid] = dec_h;           // own column, no sync needed
            float y1 = dv1*dec_h;
            #pragma unroll
            for (int d=0; d<16; d++){
                float uv = (s-d >= 0) ? hist[(s-d) & 15][tid] : 0.f;
                y1 = fmaf(K1d[d], uv, y1);
            }
            ast(&ygel1[(size_t)b*H + tid], gelu_f(y1));
        }
        gbar_grp(gfl, g++, tid);
        // ===== D: GEMV1 + GLU =====
        ysh[tid] = ald(&ygel1[(size_t)b*H + tid]);
        __syncthreads();
        {
            float za = 0.f, zb = 0.f;
            const unsigned short* base = WB1 + (size_t)(ks*128)*H2 + col;
            #pragma unroll 8
            for (int k=0;k<128;k++){
                float y = ysh[ks*128 + k];
                za = fmaf(y, bf2f((short)base[(size_t)k*H2]),        za);
                zb = fmaf(y, bf2f((short)base[(size_t)k*H2 + 1024]), zb);
            }
            part[0][ks][pr] = za; part[1][ks][pr] = zb;
        }
        __syncthreads();
        if (tid < 128){
            float sa=0.f, sb=0.f;
            #pragma unroll
            for (int q=0;q<8;q++){ sa += part[0][q][tid]; sb += part[1][q][tid]; }
            ast(&glud1[(size_t)b*H + col], (sa + ba1) * sigm_f(sb + bb1));
        }
        gbar_grp(gfl, g++, tid);
    }
    // ===== tail: leader: LN1+head of step 15 -> out[15] =====
    if (leader){
        float x = 2.f * ald(&glud1[(size_t)b*H + tid]);   // step 15 != 0
        float su = x, qu = x*x;
        #pragma unroll
        for (int m=32;m>=1;m>>=1){ su += __shfl_xor(su,m,64); qu += __shfl_xor(qu,m,64); }
        if (lane==0){ red[wv]=su; red[16+wv]=qu; }
        __syncthreads();
        float S=0.f, Q=0.f;
        #pragma unroll
        for (int i=0;i<16;i++){ S += red[i]; Q += red[16+i]; }
        float mean = S*(1.f/H), var = Q*(1.f/H)-mean*mean;
        float rstd = rsqrtf(var + 1e-5f);
        float d1 = (x-mean)*rstd*lg1 + be1 + cvx;
        float hp = d1*hw;
        #pragma unroll
        for (int m=32;m>=1;m>>=1) hp += __shfl_xor(hp,m,64);
        __syncthreads();
        if (lane==0) red[wv] = hp;
        __syncthreads();
        float hs = 0.f;
        #pragma unroll
        for (int i=0;i<16;i++) hs += red[i];
        if (tid==0) out[b*NSTEPS + 15] = sigm_f(hs + hb);
    }
}

extern "C" void kernel_launch(void* const* d_in, const int* in_sizes, int n_in,
                              void* d_out, int out_size, void* d_ws, size_t ws_size,
                              hipStream_t stream) {
    const float* in_seq = (const float*)d_in[0];
    const float* inw  = (const float*)d_in[2];
    const float* inb  = (const float*)d_in[3];
    const float* log_dt = (const float*)d_in[4];
    const float* Are = (const float*)d_in[5];
    const float* Aim = (const float*)d_in[6];
    const float* Bre = (const float*)d_in[7];
    const float* Bim = (const float*)d_in[8];
    const float* Cre = (const float*)d_in[9];
    const float* Cim = (const float*)d_in[10];
    const float* Dv  = (const float*)d_in[11];
    const float* outw = (const float*)d_in[12];
    const float* outb = (const float*)d_in[13];
    const float* lng = (const float*)d_in[14];
    const float* lnb = (const float*)d_in[15];
    const float* headw = (const float*)d_in[16];
    const float* headb = (const float*)d_in[17];
    float* out = (float*)d_out;

    float* ws = (float*)d_ws;
    size_t off = 0;
    auto alloc = [&](size_t n){ float* p = ws + off; off += n; return p; };
    float* dAr = alloc((size_t)LAYN*H*NST);
    float* dAi = alloc((size_t)LAYN*H*NST);
    float* dBr = alloc((size_t)LAYN*H*NST);
    float* dBi = alloc((size_t)LAYN*H*NST);
    float* Kbuf = alloc((size_t)LAYN*H*TLEN);
    float* bufA = alloc((size_t)BSZ*TLEN*H);                              // 67MB
    float* bufB = alloc((size_t)BSZ*TLEN*H);                              // 67MB
    __hip_bfloat16* gbf = (__hip_bfloat16*)alloc((size_t)BSZ*TLEN*H/2);   // 33.5MB
    __hip_bfloat16* Abf = (__hip_bfloat16*)alloc((size_t)BSZ*TLEN*H/2);   // 33.5MB
    __hip_bfloat16* Wt  = (__hip_bfloat16*)alloc((size_t)LAYN*H*H2/2);    // 8.4MB
    __hip_bfloat16* Wdb = (__hip_bfloat16*)alloc((size_t)LAYN*H*H2/2);    // 8.4MB
    float* ctx = alloc((size_t)BSZ*H);
    float* ygel0 = alloc((size_t)BSZ*H);
    float* ygel1 = alloc((size_t)BSZ*H);
    float* glud0 = alloc((size_t)BSZ*H);
    float* glud1 = alloc((size_t)BSZ*H);
    int*   flags = (int*)alloc((size_t)BSZ*GBLK*FLAGSTRIDE);
    // total ~225 MB (round-3's proven 241.7 MB OK; round-4's 283.6 MB crashed)

    k_precompute<<<(LAYN*H*NST+255)/256, 256, 0, stream>>>(log_dt,Are,Aim,Bre,Bim,dAr,dAi,dBr,dBi);
    k_genK<<<LAYN*H, 64, 0, stream>>>(dAr,dAi,dBr,dBi,Cre,Cim,Kbuf);
    k_wtr<<<dim3(H2/32, H/32, LAYN), 256, 0, stream>>>(outw, Wt);
    k_wcast<<<(LAYN*H*H2)/256, 256, 0, stream>>>(outw, Wdb);
    k_inproj_x <<<(BSZ*TLEN*H)/256, 256, 0, stream>>>(in_seq, inw, inb, bufA);
    k_inproj_xT<<<(BSZ*TLEN*H)/256, 256, 0, stream>>>(in_seq, inw, inb, bufB);

    // ---- layer 0: res = bufA (b,t,h); xT = bufB (b,h,t)
    k_conv<<<dim3(TLEN/CTT, H), 256, 0, stream>>>(bufB, Kbuf, Dv, gbf, 0);
    k_trcast_bf<<<dim3(TLEN/32, H/32, BSZ), 256, 0, stream>>>(gbf, Abf);
    k_gemm_glu_mfma<<<dim3(BSZ*TLEN/128, H/64), 256, 0, stream>>>(Abf, Wt, outb, bufB);
    k_ln<<<BSZ*TLEN, 256, 0, stream>>>(bufB, bufA, lng, lnb, bufA);
    k_transpose<<<dim3(16,32,32), 256, 0, stream>>>(bufA, bufB);

    // ---- layer 1
    k_conv<<<dim3(TLEN/CTT, H), 256, 0, stream>>>(bufB, Kbuf, Dv, gbf, 1);
    k_trcast_bf<<<dim3(TLEN/32, H/32, BSZ), 256, 0, stream>>>(gbf, Abf);
    k_gemm_glu_mfma<<<dim3(BSZ*TLEN/128, H/64), 256, 0, stream>>>(Abf, Wt + (size_t)H*H2, outb + H2, bufB);
    k_ln<<<BSZ*TLEN, 256, 0, stream>>>(bufB, bufA, lng+H, lnb+H, bufA);

    k_ctx<<<(BSZ*H)/256, 256, 0, stream>>>(bufA, ctx);

    // ---- decode: 32 independent same-XCD groups, group-local barriers only
    hipMemsetAsync(flags, 0, sizeof(int)*(size_t)BSZ*GBLK*FLAGSTRIDE, stream);
    k_decode<<<BSZ*GBLK, 1024, 0, stream>>>(Kbuf, Dv, Wdb, outb, lng, lnb,
                                            ctx, headw, headb,
                                            ygel0, ygel1, glud0, glud1, out, flags);
}

// Round 14
// 1489.065 us; speedup vs baseline: 3.8808x; 1.3878x over previous
//
#include <hip/hip_runtime.h>
#include <hip/hip_bf16.h>
#include <math.h>

#define H    1024
#define NST  64
#define LAYN 2
#define BSZ  32
#define TLEN 512
#define NSTEPS 16
#define H2   2048
#define FLAGSTRIDE 32
#define NGRP 8

typedef __attribute__((ext_vector_type(8))) short bf16x8;
typedef __attribute__((ext_vector_type(4))) float f32x4;

__device__ __forceinline__ float gelu_f(float x){
    return 0.5f*x*(1.0f+erff(x*0.7071067811865475f));
}
__device__ __forceinline__ float sigm_f(float x){
    return 1.0f/(1.0f+expf(-x));
}
__device__ __forceinline__ short bfbits(float x){
    __hip_bfloat16 h = __float2bfloat16(x);
    return *(short*)&h;
}
__device__ __forceinline__ float bf2f(short s){
    unsigned int u = ((unsigned int)(unsigned short)s) << 16;
    return __uint_as_float(u);
}
__device__ __forceinline__ void gload16(const void* g, void* l){
    __builtin_amdgcn_global_load_lds((const __attribute__((address_space(1))) void*)g,
                                     (__attribute__((address_space(3))) void*)l, 16, 0, 0);
}
// relaxed agent-scope data path (validated round 12/13)
__device__ __forceinline__ void ast(float* p, float v){
    __hip_atomic_store(p, v, __ATOMIC_RELAXED, __HIP_MEMORY_SCOPE_AGENT);
}
__device__ __forceinline__ float ald(const float* p){
    return __hip_atomic_load(p, __ATOMIC_RELAXED, __HIP_MEMORY_SCOPE_AGENT);
}

// ---------------- discretized SSM params ----------------
__global__ void k_precompute(const float* __restrict__ log_dt,
                             const float* __restrict__ Are, const float* __restrict__ Aim,
                             const float* __restrict__ Bre, const float* __restrict__ Bim,
                             float* __restrict__ dAr, float* __restrict__ dAi,
                             float* __restrict__ dBr, float* __restrict__ dBi){
    int i = blockIdx.x*256 + threadIdx.x;
    if (i >= LAYN*H*NST) return;
    int lh = i / NST;
    float dt = expf(log_dt[lh]);
    float ar = Are[i], ai = Aim[i];
    float e  = expf(dt*ar);
    float sa, ca; sincosf(dt*ai, &sa, &ca);
    float dar = e*ca, dai = e*sa;
    float zr = dar-1.0f, zi = dai;
    float inv = 1.0f/(ar*ar + ai*ai);
    float wr = (zr*ar + zi*ai)*inv;
    float wi = (zi*ar - zr*ai)*inv;
    float br = Bre[i], bi = Bim[i];
    dAr[i]=dar; dAi[i]=dai;
    dBr[i]=wr*br - wi*bi;
    dBi[i]=wr*bi + wi*br;
}

// ---------------- in_proj ----------------
__global__ void k_inproj_x(const float* __restrict__ in, const float* __restrict__ w,
                           const float* __restrict__ bias, float* __restrict__ x){
    int i = blockIdx.x*256+threadIdx.x;          // b*T*H + t*H + h
    int h = i & (H-1);
    int bt = i >> 10;
    x[i] = in[bt]*w[h] + bias[h];
}
__global__ void k_inproj_xT(const float* __restrict__ in, const float* __restrict__ w,
                            const float* __restrict__ bias, float* __restrict__ xT){
    int i = blockIdx.x*256+threadIdx.x;          // b*H*T + h*T + t
    int t = i & (TLEN-1);
    int bh = i >> 9;
    int h = bh & (H-1);
    int b = bh >> 10;
    xT[i] = in[b*TLEN + t]*w[h] + bias[h];
}

// ---------------- S4 conv kernel gen ----------------
__global__ __launch_bounds__(64) void k_genK(
        const float* __restrict__ dAr, const float* __restrict__ dAi,
        const float* __restrict__ dBr, const float* __restrict__ dBi,
        const float* __restrict__ Cre, const float* __restrict__ Cim,
        float* __restrict__ Kbuf){
    __shared__ float trans[16][65];
    int lh = blockIdx.x;
    int lane = threadIdx.x;
    int pi = lh*NST + lane;
    float ar=dAr[pi], ai=dAi[pi];
    float br=dBr[pi], bi=dBi[pi];
    float cr=2.f*Cre[pi], ci=2.f*Cim[pi];
    float wr = cr*br - ci*bi;
    float wi = cr*bi + ci*br;
    float* Krow = Kbuf + (size_t)lh*TLEN;
    int r = lane>>2, q = lane&3;
    for (int c=0;c<TLEN/16;c++){
        #pragma unroll
        for (int i=0;i<16;i++){
            trans[i][lane] = wr;
            float nr = fmaf(wr,ar, -wi*ai);
            float ni = fmaf(wr,ai,  wi*ar);
            wr=nr; wi=ni;
        }
        __syncthreads();
        float s = 0.f;
        #pragma unroll
        for (int m=0;m<16;m++) s += trans[r][q*16+m];
        s += __shfl_xor(s,1,64);
        s += __shfl_xor(s,2,64);
        if (q==0) Krow[c*16 + r] = s;
        __syncthreads();
    }
}

// ---------------- causal Toeplitz conv + D*u + gelu; bf16 (B,H,T) out ----------------
#define CTT 256
#define CJT 64
__global__ __launch_bounds__(256) void k_conv(
        const float* __restrict__ u,            // (B,H,T) f32
        const float* __restrict__ Kbuf,         // (L,H,T)
        const float* __restrict__ Dv,
        __hip_bfloat16* __restrict__ g,         // (B,H,T) bf16
        int layer){
    __shared__ float u_s[CJT][33];
    __shared__ float Ks[CTT+CJT];
    int h  = blockIdx.y;
    int t0 = blockIdx.x * CTT;
    int tid = threadIdx.x;
    int bg = tid & 7;
    int tg = tid >> 3;
    const float* Krow = Kbuf + ((size_t)layer*H + h)*TLEN;
    float acc[8][4];
    #pragma unroll
    for (int i=0;i<8;i++){
        #pragma unroll
        for (int b=0;b<4;b++) acc[i][b]=0.f;
    }
    int ntile = t0/CJT + CTT/CJT;
    for (int jt=0; jt<ntile; jt++){
        int j0 = jt*CJT;
        __syncthreads();
        for (int i=tid; i<CTT+CJT; i+=256){
            int d = t0 - j0 - (CJT-1) + i;
            Ks[i] = (d>=0) ? Krow[d] : 0.f;
        }
        {
            int jj = tid & 63, bq = tid >> 6;
            #pragma unroll
            for (int p=0;p<8;p++){
                int b = bq + p*4;
                u_s[jj][b] = u[((size_t)b*H + h)*TLEN + j0 + jj];
            }
        }
        __syncthreads();
        #pragma unroll 8
        for (int j=0;j<CJT;j++){
            float4 ub = *(const float4*)&u_s[j][bg*4];
            int base = tg*8 + (CJT-1) - j;
            float kv[8];
            #pragma unroll
            for (int i=0;i<8;i++) kv[i] = Ks[base+i];
            #pragma unroll
            for (int i=0;i<8;i++){
                acc[i][0] = fmaf(kv[i], ub.x, acc[i][0]);
                acc[i][1] = fmaf(kv[i], ub.y, acc[i][1]);
                acc[i][2] = fmaf(kv[i], ub.z, acc[i][2]);
                acc[i][3] = fmaf(kv[i], ub.w, acc[i][3]);
            }
        }
    }
    float dv = Dv[layer*H + h];
    int tb = t0 + tg*8;
    #pragma unroll
    for (int b=0;b<4;b++){
        int bb = bg*4 + b;
        const float* urow = u + ((size_t)bb*H + h)*TLEN + tb;
        float4 u0 = *(const float4*)urow;
        float4 u1 = *(const float4*)(urow+4);
        bf16x8 o;
        o[0] = bfbits(gelu_f(fmaf(dv,u0.x, acc[0][b])));
        o[1] = bfbits(gelu_f(fmaf(dv,u0.y, acc[1][b])));
        o[2] = bfbits(gelu_f(fmaf(dv,u0.z, acc[2][b])));
        o[3] = bfbits(gelu_f(fmaf(dv,u0.w, acc[3][b])));
        o[4] = bfbits(gelu_f(fmaf(dv,u1.x, acc[4][b])));
        o[5] = bfbits(gelu_f(fmaf(dv,u1.y, acc[5][b])));
        o[6] = bfbits(gelu_f(fmaf(dv,u1.z, acc[6][b])));
        o[7] = bfbits(gelu_f(fmaf(dv,u1.w, acc[7][b])));
        *(bf16x8*)(g + ((size_t)bb*H + h)*TLEN + tb) = o;
    }
}

// ---------------- bf16 transpose (B,H,T) -> (B,T,H) ----------------
__global__ __launch_bounds__(256) void k_trcast_bf(const __hip_bfloat16* __restrict__ x,
                                                   __hip_bfloat16* __restrict__ y){
    __shared__ __hip_bfloat16 tile[32][34];
    int t0 = blockIdx.x*32, h0 = blockIdx.y*32, b = blockIdx.z;
    int tx = threadIdx.x & 31, ty = threadIdx.x >> 5;
    #pragma unroll
    for (int i=0;i<32;i+=8)
        tile[ty+i][tx] = x[((size_t)(b*H + h0+ty+i))*TLEN + t0+tx];
    __syncthreads();
    #pragma unroll
    for (int i=0;i<32;i+=8)
        y[((size_t)(b*TLEN + t0+ty+i))*H + h0+tx] = tile[tx][ty+i];
}

// ---------------- transpose (b,t,h) -> (b,h,t) f32 ----------------
__global__ __launch_bounds__(256) void k_transpose(const float* __restrict__ x, float* __restrict__ xT){
    __shared__ float tile[32][33];
    int t0 = blockIdx.x*32, h0 = blockIdx.y*32, b = blockIdx.z;
    int tx = threadIdx.x & 31, ty = threadIdx.x >> 5;
    #pragma unroll
    for (int i=0;i<32;i+=8)
        tile[ty+i][tx] = x[((size_t)(b*TLEN + t0+ty+i))*H + h0+tx];
    __syncthreads();
    #pragma unroll
    for (int i=0;i<32;i+=8)
        xT[((size_t)(b*H + h0+ty+i))*TLEN + t0+tx] = tile[tx][ty+i];
}

// ---------------- W (L,H,2H) f32 -> Wt (L,2H,H) bf16 ----------------
__global__ __launch_bounds__(256) void k_wtr(const float* __restrict__ W,
                                             __hip_bfloat16* __restrict__ Wt){
    __shared__ float tile[32][33];
    int n0 = blockIdx.x*32, k0 = blockIdx.y*32, l = blockIdx.z;
    const float* Wl = W + (size_t)l*H*H2;
    __hip_bfloat16* Wtl = Wt + (size_t)l*H*H2;
    int tx = threadIdx.x & 31, ty = threadIdx.x >> 5;
    #pragma unroll
    for (int i=0;i<32;i+=8)
        tile[ty+i][tx] = Wl[(size_t)(k0+ty+i)*H2 + n0+tx];
    __syncthreads();
    #pragma unroll
    for (int i=0;i<32;i+=8)
        Wtl[(size_t)(n0+ty+i)*H + k0+tx] = __float2bfloat16(tile[tx][ty+i]);
}

// ---------------- bf16 MFMA GEMM + bias + GLU fused (encoder) ----------------
__global__ __launch_bounds__(256) void k_gemm_glu_mfma(
        const __hip_bfloat16* __restrict__ Abf,
        const __hip_bfloat16* __restrict__ Wt,
        const float* __restrict__ bias2,         // (2048,)
        float* __restrict__ glu){                // (M,1024)
    __shared__ alignas(16) short As[128*32];
    __shared__ alignas(16) short Bs[128*32];
    const int K = 1024;
    int tid = threadIdx.x;
    int lane = tid & 63, wid = tid >> 6;
    int m0 = blockIdx.x * 128;
    int nb = blockIdx.y * 64;
    int g0 = tid, g1 = tid + 256;
    int r0 = g0 >> 2, r1 = g1 >> 2;
    int wtr0 = nb + ((r0>>6)<<5) + (r0&31) + ((r0>>5)&1)*1024;
    int wtr1 = nb + ((r1>>6)<<5) + (r1&31) + ((r1>>5)&1)*1024;
    const short* Ap = (const short*)Abf;
    const short* Bp = (const short*)Wt;
    const short* Ag0 = Ap + (size_t)(m0 + r0)*K + (g0&3)*8;
    const short* Ag1 = Ap + (size_t)(m0 + r1)*K + (g1&3)*8;
    const short* Bg0 = Bp + (size_t)wtr0*K + (g0&3)*8;
    const short* Bg1 = Bp + (size_t)wtr1*K + (g1&3)*8;
    char* AsB = (char*)As;
    char* BsB = (char*)Bs;
    int wr = wid >> 1, wc = wid & 1;
    int mo = wr*64, no = wc*64;
    f32x4 acc[4][4] = {};
    int arow = (lane & 15)*32 + (lane>>4)*8;
    for (int k0 = 0; k0 < K; k0 += 32){
        gload16(Ag0 + k0, AsB + wid*1024);
        gload16(Ag1 + k0, AsB + 4096 + wid*1024);
        gload16(Bg0 + k0, BsB + wid*1024);
        gload16(Bg1 + k0, BsB + 4096 + wid*1024);
        asm volatile("s_waitcnt vmcnt(0)" ::: "memory");
        __syncthreads();
        bf16x8 a[4], b[4];
        #pragma unroll
        for (int mi=0;mi<4;mi++)
            a[mi] = *(const bf16x8*)(As + (mo + mi*16)*32 + arow);
        #pragma unroll
        for (int ni=0;ni<4;ni++)
            b[ni] = *(const bf16x8*)(Bs + (no + ni*16)*32 + arow);
        #pragma unroll
        for (int mi=0;mi<4;mi++){
            #pragma unroll
            for (int ni=0;ni<4;ni++){
                acc[mi][ni] = __builtin_amdgcn_mfma_f32_16x16x32_bf16(a[mi], b[ni], acc[mi][ni], 0, 0, 0);
            }
        }
        __syncthreads();
    }
    int cbase = nb + wc*32 + (lane&15);
    #pragma unroll
    for (int ni=0;ni<2;ni++){
        int c = cbase + ni*16;
        float ba = bias2[c], bb = bias2[c+1024];
        #pragma unroll
        for (int mi=0;mi<4;mi++){
            #pragma unroll
            for (int r=0;r<4;r++){
                size_t m = m0 + mo + mi*16 + (lane>>4)*4 + r;
                float za = acc[mi][ni][r] + ba;
                float zb = acc[mi][ni+2][r] + bb;
                glu[m*H + c] = za * sigm_f(zb);
            }
        }
    }
}

// ---------------- LayerNorm over H per (b,t) row (encoder) ----------------
__global__ __launch_bounds__(256) void k_ln(const float* __restrict__ glu, const float* __restrict__ res,
        const float* __restrict__ gamma, const float* __restrict__ beta, float* __restrict__ outx){
    __shared__ float red[8];
    int row = blockIdx.x;
    int tid = threadIdx.x;
    float4 gv = *(const float4*)(glu + (size_t)row*H + tid*4);
    float4 rv = *(const float4*)(res + (size_t)row*H + tid*4);
    float x0=gv.x+rv.x, x1=gv.y+rv.y, x2=gv.z+rv.z, x3=gv.w+rv.w;
    float s = x0+x1+x2+x3;
    float q = x0*x0+x1*x1+x2*x2+x3*x3;
    #pragma unroll
    for (int m=32;m>=1;m>>=1){ s += __shfl_xor(s,m,64); q += __shfl_xor(q,m,64); }
    int wv = tid>>6;
    if ((tid&63)==0){ red[wv]=s; red[4+wv]=q; }
    __syncthreads();
    s = red[0]+red[1]+red[2]+red[3];
    q = red[4]+red[5]+red[6]+red[7];
    float m = s*(1.0f/H);
    float v = q*(1.0f/H) - m*m;
    float rstd = rsqrtf(v + 1e-5f);
    float4 gm = *(const float4*)(gamma + tid*4);
    float4 bt = *(const float4*)(beta + tid*4);
    float4 o;
    o.x = (x0-m)*rstd*gm.x + bt.x;
    o.y = (x1-m)*rstd*gm.y + bt.y;
    o.z = (x2-m)*rstd*gm.z + bt.z;
    o.w = (x3-m)*rstd*gm.w + bt.w;
    *(float4*)(outx + (size_t)row*H + tid*4) = o;
}

__global__ void k_ctx(const float* __restrict__ x, float* __restrict__ ctx){
    int i = blockIdx.x*256+threadIdx.x;
    int b = i>>10, h = i&(H-1);
    ctx[i] = x[((size_t)(b*TLEN + TLEN-1))*H + h];
}

// ======================= GROUP-LOCAL DECODE, 4 BATCHES/GROUP =======================
// 8 groups (one per XCD via %8 heuristic) x 32 blocks x 256 threads.
// Group g owns batches 4g..4g+3. Leader blocks jj=0..3 do vector phases (1 batch
// each, Toeplitz formulation); all 32 blocks do GEMM phases with W applied to 4
// batches per line read (bf16 Wt rows, k-contiguous dwordx4 streams).
__device__ __forceinline__ void gbar_grp(int* gfl, int jj, int g, int tid){
    __syncthreads();   // drains vmcnt per wave -> block's global stores done
    if (tid == 0)
        __hip_atomic_store(gfl + jj*FLAGSTRIDE, g, __ATOMIC_RELAXED,
                           __HIP_MEMORY_SCOPE_AGENT);
    if (tid < 32){
        int it = 0;
        while (__hip_atomic_load(gfl + tid*FLAGSTRIDE, __ATOMIC_RELAXED,
                                 __HIP_MEMORY_SCOPE_AGENT) < g){
            __builtin_amdgcn_s_sleep(1);
            if (++it > 1000000) break;   // escape: wrong answer, not hang
        }
    }
    __syncthreads();
}

// GEMM phase: 4 batches x (1024x2048) x GLU. thread = (p=tid&31, ks=tid>>5).
__device__ __forceinline__ void gemv4(int grp, int jj, int tid,
        float (*ysh)[H], float (*part)[32][8],
        const short* __restrict__ Wl, const float* __restrict__ b2,
        const float* __restrict__ ygel, float* __restrict__ glud){
    #pragma unroll
    for (int i=0;i<16;i++){
        int idx = i*256 + tid;
        int b4 = idx >> 10, hh = idx & 1023;
        ysh[b4][hh] = ald(&ygel[(size_t)(4*grp + b4)*H + hh]);
    }
    __syncthreads();
    int p = tid & 31, ks = tid >> 5;
    int colp = jj*32 + p;
    const short* wza = Wl + (size_t)colp*H + ks*128;
    const short* wzb = Wl + (size_t)(colp+1024)*H + ks*128;
    float a0=0,a1=0,a2=0,a3=0, c0=0,c1=0,c2=0,c3=0;
    const float* u0 = &ysh[0][ks*128];
    const float* u1 = &ysh[1][ks*128];
    const float* u2 = &ysh[2][ks*128];
    const float* u3 = &ysh[3][ks*128];
    for (int kk=0; kk<128; kk+=8){
        bf16x8 wa = *(const bf16x8*)(wza + kk);
        bf16x8 wb = *(const bf16x8*)(wzb + kk);
        #pragma unroll
        for (int j=0;j<8;j++){
            float wav = bf2f(wa[j]), wbv = bf2f(wb[j]);
            float y0 = u0[kk+j], y1 = u1[kk+j], y2 = u2[kk+j], y3 = u3[kk+j];
            a0 = fmaf(y0, wav, a0);  c0 = fmaf(y0, wbv, c0);
            a1 = fmaf(y1, wav, a1);  c1 = fmaf(y1, wbv, c1);
            a2 = fmaf(y2, wav, a2);  c2 = fmaf(y2, wbv, c2);
            a3 = fmaf(y3, wav, a3);  c3 = fmaf(y3, wbv, c3);
        }
    }
    __syncthreads();
    part[ks][p][0]=a0; part[ks][p][1]=c0;
    part[ks][p][2]=a1; part[ks][p][3]=c1;
    part[ks][p][4]=a2; part[ks][p][5]=c2;
    part[ks][p][6]=a3; part[ks][p][7]=c3;
    __syncthreads();
    if (tid < 128){
        int p2 = tid & 31, b4 = tid >> 5;
        int c2 = jj*32 + p2;
        float sa=0.f, sb=0.f;
        #pragma unroll
        for (int q=0;q<8;q++){ sa += part[q][p2][b4*2]; sb += part[q][p2][b4*2+1]; }
        float za = sa + b2[c2];
        float zb = sb + b2[1024 + c2];
        ast(&glud[(size_t)(4*grp + b4)*H + c2], za * sigm_f(zb));
    }
}

__global__ __launch_bounds__(256, 1) void k_decode(
        const float* __restrict__ Kbuf, const float* __restrict__ Dv,
        const __hip_bfloat16* __restrict__ Wt, const float* __restrict__ bias2,
        const float* __restrict__ lng, const float* __restrict__ lnb,
        const float* __restrict__ ctx, const float* __restrict__ headw,
        const float* __restrict__ headb,
        float* __restrict__ ygel0, float* __restrict__ ygel1,
        float* __restrict__ glud0, float* __restrict__ glud1,
        float* __restrict__ out, int* __restrict__ flags){
    __shared__ float hist[16][H];        // 64KB: leader's dec history
    __shared__ float ysh[4][H];          // 16KB
    __shared__ float part[8][32][8];     // 8KB
    __shared__ float red[8];
    __shared__ float bitsh[16];
    int bid = blockIdx.x;
    int grp = bid & 7, jj = bid >> 3;
    int tid = threadIdx.x;
    int lane = tid & 63, wv = tid >> 6;
    bool leader = (jj < 4);
    int b = grp*4 + jj;                  // leader's batch (valid when jj<4)
    // leader per-h params (float4 across h = tid*4..+3)
    float4 dv0v, dv1v, lg0v, be0v, lg1v, be1v, cvxv, hwv;
    float hb = headb[0];
    if (leader){
        dv0v = *(const float4*)(Dv + tid*4);
        dv1v = *(const float4*)(Dv + H + tid*4);
        lg0v = *(const float4*)(lng + tid*4);
        be0v = *(const float4*)(lnb + tid*4);
        lg1v = *(const float4*)(lng + H + tid*4);
        be1v = *(const float4*)(lnb + H + tid*4);
        cvxv = *(const float4*)(ctx + (size_t)b*H + tid*4);
        hwv  = *(const float4*)(headw + tid*4);
    }
    if (tid < 16) bitsh[tid] = 0.f;
    __syncthreads();
    const short* Wt0 = (const short*)Wt;
    const short* Wt1 = (const short*)Wt + (size_t)H*H2;
    int* gfl = flags + grp*32*FLAGSTRIDE;
    int g = 1;
    for (int s=0; s<NSTEPS; s++){
        // ===== A: leader: LN1+head(prev) -> bit; conv0 -> ygel0 =====
        if (leader){
            if (s > 0){
                int sp = s-1;
                float x0 = ald(&glud1[(size_t)b*H + tid*4+0]);
                float x1 = ald(&glud1[(size_t)b*H + tid*4+1]);
                float x2 = ald(&glud1[(size_t)b*H + tid*4+2]);
                float x3 = ald(&glud1[(size_t)b*H + tid*4+3]);
                if (sp != 0){ x0*=2.f; x1*=2.f; x2*=2.f; x3*=2.f; }
                float su = x0+x1+x2+x3, qu = x0*x0+x1*x1+x2*x2+x3*x3;
                #pragma unroll
                for (int m=32;m>=1;m>>=1){ su += __shfl_xor(su,m,64); qu += __shfl_xor(qu,m,64); }
                if (lane==0){ red[wv]=su; red[4+wv]=qu; }
                __syncthreads();
                float S = red[0]+red[1]+red[2]+red[3];
                float Q = red[4]+red[5]+red[6]+red[7];
                float mean = S*(1.f/H), var = Q*(1.f/H)-mean*mean;
                float rstd = rsqrtf(var + 1e-5f);
                float d0 = (x0-mean)*rstd*lg1v.x + be1v.x + cvxv.x;
                float d1 = (x1-mean)*rstd*lg1v.y + be1v.y + cvxv.y;
                float d2 = (x2-mean)*rstd*lg1v.z + be1v.z + cvxv.z;
                float d3 = (x3-mean)*rstd*lg1v.w + be1v.w + cvxv.w;
                float hp = d0*hwv.x + d1*hwv.y + d2*hwv.z + d3*hwv.w;
                #pragma unroll
                for (int m=32;m>=1;m>>=1) hp += __shfl_xor(hp,m,64);
                __syncthreads();
                if (lane==0) red[wv] = hp;
                __syncthreads();
                float hs = red[0]+red[1]+red[2]+red[3] + hb;
                float bit = sigm_f(hs);
                if (tid==0){ out[b*NSTEPS + sp] = bit; bitsh[sp] = bit; }
                __syncthreads();
            }
            float bu = (s==0) ? 0.f : bitsh[s-1];
            float dvs[4] = {dv0v.x, dv0v.y, dv0v.z, dv0v.w};
            #pragma unroll
            for (int i=0;i<4;i++){
                int h = tid*4+i;
                const float* Kr = Kbuf + (size_t)h*TLEN;
                float y0 = dvs[i]*bu;
                #pragma unroll
                for (int d=0; d<16; d++){
                    int idx = s-1-d;
                    float uv = (idx >= 0) ? bitsh[idx] : 0.f;
                    y0 = fmaf(Kr[d], uv, y0);
                }
                ast(&ygel0[(size_t)b*H + h], gelu_f(y0));
            }
        }
        gbar_grp(gfl, jj, g++, tid);
        // ===== B: GEMM0 x4 batches =====
        gemv4(grp, jj, tid, ysh, part, Wt0, bias2, ygel0, glud0);
        gbar_grp(gfl, jj, g++, tid);
        // ===== C: leader: LN0 -> dec; hist push; conv1 -> ygel1 =====
        if (leader){
            float x0 = ald(&glud0[(size_t)b*H + tid*4+0]);
            float x1 = ald(&glud0[(size_t)b*H + tid*4+1]);
            float x2 = ald(&glud0[(size_t)b*H + tid*4+2]);
            float x3 = ald(&glud0[(size_t)b*H + tid*4+3]);
            if (s != 0){ x0*=2.f; x1*=2.f; x2*=2.f; x3*=2.f; }
            float su = x0+x1+x2+x3, qu = x0*x0+x1*x1+x2*x2+x3*x3;
            #pragma unroll
            for (int m=32;m>=1;m>>=1){ su += __shfl_xor(su,m,64); qu += __shfl_xor(qu,m,64); }
            if (lane==0){ red[wv]=su; red[4+wv]=qu; }
            __syncthreads();
            float S = red[0]+red[1]+red[2]+red[3];
            float Q = red[4]+red[5]+red[6]+red[7];
            float mean = S*(1.f/H), var = Q*(1.f/H)-mean*mean;
            float rstd = rsqrtf(var + 1e-5f);
            float dd[4];
            dd[0] = (x0-mean)*rstd*lg0v.x + be0v.x;
            dd[1] = (x1-mean)*rstd*lg0v.y + be0v.y;
            dd[2] = (x2-mean)*rstd*lg0v.z + be0v.z;
            dd[3] = (x3-mean)*rstd*lg0v.w + be0v.w;
            float dvs[4] = {dv1v.x, dv1v.y, dv1v.z, dv1v.w};
            #pragma unroll
            for (int i=0;i<4;i++){
                int h = tid*4+i;
                hist[s & 15][h] = dd[i];
                const float* Kr = Kbuf + (size_t)(H+h)*TLEN;
                float y1 = dvs[i]*dd[i];
                #pragma unroll
                for (int d=0; d<16; d++){
                    int sd = s-d;
                    float uv = (sd >= 0) ? hist[sd & 15][h] : 0.f;
                    y1 = fmaf(Kr[d], uv, y1);
                }
                ast(&ygel1[(size_t)b*H + h], gelu_f(y1));
            }
        }
        gbar_grp(gfl, jj, g++, tid);
        // ===== D: GEMM1 x4 batches =====
        gemv4(grp, jj, tid, ysh, part, Wt1, bias2 + H2, ygel1, glud1);
        gbar_grp(gfl, jj, g++, tid);
    }
    // ===== tail: leader: LN1+head of step 15 =====
    if (leader){
        float x0 = 2.f*ald(&glud1[(size_t)b*H + tid*4+0]);
        float x1 = 2.f*ald(&glud1[(size_t)b*H + tid*4+1]);
        float x2 = 2.f*ald(&glud1[(size_t)b*H + tid*4+2]);
        float x3 = 2.f*ald(&glud1[(size_t)b*H + tid*4+3]);
        float su = x0+x1+x2+x3, qu = x0*x0+x1*x1+x2*x2+x3*x3;
        #pragma unroll
        for (int m=32;m>=1;m>>=1){ su += __shfl_xor(su,m,64); qu += __shfl_xor(qu,m,64); }
        if (lane==0){ red[wv]=su; red[4+wv]=qu; }
        __syncthreads();
        float S = red[0]+red[1]+red[2]+red[3];
        float Q = red[4]+red[5]+red[6]+red[7];
        float mean = S*(1.f/H), var = Q*(1.f/H)-mean*mean;
        float rstd = rsqrtf(var + 1e-5f);
        float d0 = (x0-mean)*rstd*lg1v.x + be1v.x + cvxv.x;
        float d1 = (x1-mean)*rstd*lg1v.y + be1v.y + cvxv.y;
        float d2 = (x2-mean)*rstd*lg1v.z + be1v.z + cvxv.z;
        float d3 = (x3-mean)*rstd*lg1v.w + be1v.w + cvxv.w;
        float hp = d0*hwv.x + d1*hwv.y + d2*hwv.z + d3*hwv.w;
        #pragma unroll
        for (int m=32;m>=1;m>>=1) hp += __shfl_xor(hp,m,64);
        __syncthreads();
        if (lane==0) red[wv] = hp;
        __syncthreads();
        float hs = red[0]+red[1]+red[2]+red[3] + hb;
        if (tid==0) out[b*NSTEPS + 15] = sigm_f(hs);
    }
}

extern "C" void kernel_launch(void* const* d_in, const int* in_sizes, int n_in,
                              void* d_out, int out_size, void* d_ws, size_t ws_size,
                              hipStream_t stream) {
    const float* in_seq = (const float*)d_in[0];
    const float* inw  = (const float*)d_in[2];
    const float* inb  = (const float*)d_in[3];
    const float* log_dt = (const float*)d_in[4];
    const float* Are = (const float*)d_in[5];
    const float* Aim = (const float*)d_in[6];
    const float* Bre = (const float*)d_in[7];
    const float* Bim = (const float*)d_in[8];
    const float* Cre = (const float*)d_in[9];
    const float* Cim = (const float*)d_in[10];
    const float* Dv  = (const float*)d_in[11];
    const float* outw = (const float*)d_in[12];
    const float* outb = (const float*)d_in[13];
    const float* lng = (const float*)d_in[14];
    const float* lnb = (const float*)d_in[15];
    const float* headw = (const float*)d_in[16];
    const float* headb = (const float*)d_in[17];
    float* out = (float*)d_out;

    float* ws = (float*)d_ws;
    size_t off = 0;
    auto alloc = [&](size_t n){ float* p = ws + off; off += n; return p; };
    float* dAr = alloc((size_t)LAYN*H*NST);
    float* dAi = alloc((size_t)LAYN*H*NST);
    float* dBr = alloc((size_t)LAYN*H*NST);
    float* dBi = alloc((size_t)LAYN*H*NST);
    float* Kbuf = alloc((size_t)LAYN*H*TLEN);
    float* bufA = alloc((size_t)BSZ*TLEN*H);                              // 67MB
    float* bufB = alloc((size_t)BSZ*TLEN*H);                              // 67MB
    __hip_bfloat16* gbf = (__hip_bfloat16*)alloc((size_t)BSZ*TLEN*H/2);   // 33.5MB
    __hip_bfloat16* Abf = (__hip_bfloat16*)alloc((size_t)BSZ*TLEN*H/2);   // 33.5MB
    __hip_bfloat16* Wt  = (__hip_bfloat16*)alloc((size_t)LAYN*H*H2/2);    // 8.4MB
    float* ctx = alloc((size_t)BSZ*H);
    float* ygel0 = alloc((size_t)BSZ*H);
    float* ygel1 = alloc((size_t)BSZ*H);
    float* glud0 = alloc((size_t)BSZ*H);
    float* glud1 = alloc((size_t)BSZ*H);
    int*   flags = (int*)alloc((size_t)NGRP*32*FLAGSTRIDE);
    // total ~217 MB (round-3's proven 241.7 MB OK; round-4's 283.6 MB crashed)

    k_precompute<<<(LAYN*H*NST+255)/256, 256, 0, stream>>>(log_dt,Are,Aim,Bre,Bim,dAr,dAi,dBr,dBi);
    k_genK<<<LAYN*H, 64, 0, stream>>>(dAr,dAi,dBr,dBi,Cre,Cim,Kbuf);
    k_wtr<<<dim3(H2/32, H/32, LAYN), 256, 0, stream>>>(outw, Wt);
    k_inproj_x <<<(BSZ*TLEN*H)/256, 256, 0, stream>>>(in_seq, inw, inb, bufA);
    k_inproj_xT<<<(BSZ*TLEN*H)/256, 256, 0, stream>>>(in_seq, inw, inb, bufB);

    // ---- layer 0: res = bufA (b,t,h); xT = bufB (b,h,t)
    k_conv<<<dim3(TLEN/CTT, H), 256, 0, stream>>>(bufB, Kbuf, Dv, gbf, 0);
    k_trcast_bf<<<dim3(TLEN/32, H/32, BSZ), 256, 0, stream>>>(gbf, Abf);
    k_gemm_glu_mfma<<<dim3(BSZ*TLEN/128, H/64), 256, 0, stream>>>(Abf, Wt, outb, bufB);
    k_ln<<<BSZ*TLEN, 256, 0, stream>>>(bufB, bufA, lng, lnb, bufA);
    k_transpose<<<dim3(16,32,32), 256, 0, stream>>>(bufA, bufB);

    // ---- layer 1
    k_conv<<<dim3(TLEN/CTT, H), 256, 0, stream>>>(bufB, Kbuf, Dv, gbf, 1);
    k_trcast_bf<<<dim3(TLEN/32, H/32, BSZ), 256, 0, stream>>>(gbf, Abf);
    k_gemm_glu_mfma<<<dim3(BSZ*TLEN/128, H/64), 256, 0, stream>>>(Abf, Wt + (size_t)H*H2, outb + H2, bufB);
    k_ln<<<BSZ*TLEN, 256, 0, stream>>>(bufB, bufA, lng+H, lnb+H, bufA);

    k_ctx<<<(BSZ*H)/256, 256, 0, stream>>>(bufA, ctx);

    // ---- decode: 8 same-XCD groups x 4 batches, group-local barriers
    hipMemsetAsync(flags, 0, sizeof(int)*(size_t)NGRP*32*FLAGSTRIDE, stream);
    k_decode<<<NGRP*32, 256, 0, stream>>>(Kbuf, Dv, Wt, outb, lng, lnb,
                                          ctx, headw, headb,
                                          ygel0, ygel1, glud0, glud1, out, flags);
}

// Round 15
// 1236.672 us; speedup vs baseline: 4.6728x; 1.2041x over previous
//
#include <hip/hip_runtime.h>
#include <hip/hip_bf16.h>
#include <math.h>

#define H    1024
#define NST  64
#define LAYN 2
#define BSZ  32
#define TLEN 512
#define NSTEPS 16
#define H2   2048
#define FLAGSTRIDE 32
#define NGRP 8

typedef __attribute__((ext_vector_type(8))) short bf16x8;
typedef __attribute__((ext_vector_type(4))) float f32x4;

__device__ __forceinline__ float gelu_f(float x){
    return 0.5f*x*(1.0f+erff(x*0.7071067811865475f));
}
__device__ __forceinline__ float sigm_f(float x){
    return 1.0f/(1.0f+expf(-x));
}
__device__ __forceinline__ short bfbits(float x){
    __hip_bfloat16 h = __float2bfloat16(x);
    return *(short*)&h;
}
__device__ __forceinline__ float bf2f(short s){
    unsigned int u = ((unsigned int)(unsigned short)s) << 16;
    return __uint_as_float(u);
}
__device__ __forceinline__ void gload16(const void* g, void* l){
    __builtin_amdgcn_global_load_lds((const __attribute__((address_space(1))) void*)g,
                                     (__attribute__((address_space(3))) void*)l, 16, 0, 0);
}
// relaxed agent-scope data path (validated round 12/13)
__device__ __forceinline__ void ast(float* p, float v){
    __hip_atomic_store(p, v, __ATOMIC_RELAXED, __HIP_MEMORY_SCOPE_AGENT);
}
__device__ __forceinline__ float ald(const float* p){
    return __hip_atomic_load(p, __ATOMIC_RELAXED, __HIP_MEMORY_SCOPE_AGENT);
}

// ---------------- discretized SSM params ----------------
__global__ void k_precompute(const float* __restrict__ log_dt,
                             const float* __restrict__ Are, const float* __restrict__ Aim,
                             const float* __restrict__ Bre, const float* __restrict__ Bim,
                             float* __restrict__ dAr, float* __restrict__ dAi,
                             float* __restrict__ dBr, float* __restrict__ dBi){
    int i = blockIdx.x*256 + threadIdx.x;
    if (i >= LAYN*H*NST) return;
    int lh = i / NST;
    float dt = expf(log_dt[lh]);
    float ar = Are[i], ai = Aim[i];
    float e  = expf(dt*ar);
    float sa, ca; sincosf(dt*ai, &sa, &ca);
    float dar = e*ca, dai = e*sa;
    float zr = dar-1.0f, zi = dai;
    float inv = 1.0f/(ar*ar + ai*ai);
    float wr = (zr*ar + zi*ai)*inv;
    float wi = (zi*ar - zr*ai)*inv;
    float br = Bre[i], bi = Bim[i];
    dAr[i]=dar; dAi[i]=dai;
    dBr[i]=wr*br - wi*bi;
    dBi[i]=wr*bi + wi*br;
}

// ---------------- in_proj ----------------
__global__ void k_inproj_x(const float* __restrict__ in, const float* __restrict__ w,
                           const float* __restrict__ bias, float* __restrict__ x){
    int i = blockIdx.x*256+threadIdx.x;          // b*T*H + t*H + h
    int h = i & (H-1);
    int bt = i >> 10;
    x[i] = in[bt]*w[h] + bias[h];
}
__global__ void k_inproj_xT(const float* __restrict__ in, const float* __restrict__ w,
                            const float* __restrict__ bias, float* __restrict__ xT){
    int i = blockIdx.x*256+threadIdx.x;          // b*H*T + h*T + t
    int t = i & (TLEN-1);
    int bh = i >> 9;
    int h = bh & (H-1);
    int b = bh >> 10;
    xT[i] = in[b*TLEN + t]*w[h] + bias[h];
}

// ---------------- S4 conv kernel gen ----------------
__global__ __launch_bounds__(64) void k_genK(
        const float* __restrict__ dAr, const float* __restrict__ dAi,
        const float* __restrict__ dBr, const float* __restrict__ dBi,
        const float* __restrict__ Cre, const float* __restrict__ Cim,
        float* __restrict__ Kbuf){
    __shared__ float trans[16][65];
    int lh = blockIdx.x;
    int lane = threadIdx.x;
    int pi = lh*NST + lane;
    float ar=dAr[pi], ai=dAi[pi];
    float br=dBr[pi], bi=dBi[pi];
    float cr=2.f*Cre[pi], ci=2.f*Cim[pi];
    float wr = cr*br - ci*bi;
    float wi = cr*bi + ci*br;
    float* Krow = Kbuf + (size_t)lh*TLEN;
    int r = lane>>2, q = lane&3;
    for (int c=0;c<TLEN/16;c++){
        #pragma unroll
        for (int i=0;i<16;i++){
            trans[i][lane] = wr;
            float nr = fmaf(wr,ar, -wi*ai);
            float ni = fmaf(wr,ai,  wi*ar);
            wr=nr; wi=ni;
        }
        __syncthreads();
        float s = 0.f;
        #pragma unroll
        for (int m=0;m<16;m++) s += trans[r][q*16+m];
        s += __shfl_xor(s,1,64);
        s += __shfl_xor(s,2,64);
        if (q==0) Krow[c*16 + r] = s;
        __syncthreads();
    }
}

// ---------------- MFMA Toeplitz conv + D*u + gelu; bf16 (B,H,T) out ----------------
// One block per h. y[t,b] = sum_j K[t-j] u[b,j] (triangular via zero-padded Krp).
// A[t][j] = K[t-j] read as aligned bf16x8 from 8 shift-copies of Krp[x]=K[511-x].
__global__ __launch_bounds__(256, 2) void k_conv_mfma(
        const float* __restrict__ u,            // (B,H,T) f32
        const float* __restrict__ Kbuf,         // (L,H,T) f32
        const float* __restrict__ Dv,
        __hip_bfloat16* __restrict__ g,         // (B,H,T) bf16
        int layer){
    __shared__ short Krp[8][1040];   // 16.6 KB: copy c holds Krp[x+c]
    __shared__ short u_s[32][520];   // 33.3 KB: u bf16, row pad vs bank conflicts
    int h = blockIdx.x;
    int tid = threadIdx.x;
    const float* Krow = Kbuf + ((size_t)layer*H + h)*TLEN;
    for (int idx = tid; idx < 8*1040; idx += 256){
        int c = idx / 1040, y = idx - c*1040;
        int x = y + c;
        float v = (x <= 511) ? Krow[511 - x] : 0.f;
        Krp[c][y] = bfbits(v);
    }
    for (int idx = tid; idx < 32*512; idx += 256){
        int b = idx >> 9, t = idx & 511;
        u_s[b][t] = bfbits(u[((size_t)b*H + h)*TLEN + t]);
    }
    __syncthreads();
    int w = tid >> 6, lane = tid & 63;
    int m = lane & 15, q = lane >> 4;
    f32x4 acc[8][2] = {};
    for (int jt = 0; jt < 16; ++jt){
        int jtile = jt*32;
        bf16x8 b0 = *(const bf16x8*)&u_s[m][jtile + q*8];
        bf16x8 b1 = *(const bf16x8*)&u_s[16 + m][jtile + q*8];
        int mi_min = (2*jt - w + 3) >> 2;
        if (mi_min < 0) mi_min = 0;
        #pragma unroll
        for (int mi = 0; mi < 8; ++mi){
            if (mi < mi_min) continue;          // wave-uniform predicate
            int tb = (mi*4 + w)*16 + m;
            int x0 = 511 - tb + jtile + q*8;
            int c = x0 & 7, base = x0 - c;
            bf16x8 a = *(const bf16x8*)&Krp[c][base];
            acc[mi][0] = __builtin_amdgcn_mfma_f32_16x16x32_bf16(a, b0, acc[mi][0], 0,0,0);
            acc[mi][1] = __builtin_amdgcn_mfma_f32_16x16x32_bf16(a, b1, acc[mi][1], 0,0,0);
        }
    }
    float dv = Dv[layer*H + h];
    // D-layout: batch n = lane&15 (+16*nf), t = (mi*4+w)*16 + (lane>>4)*4 + r
    #pragma unroll
    for (int mi = 0; mi < 8; ++mi){
        int tb2 = (mi*4 + w)*16 + (lane>>4)*4;
        #pragma unroll
        for (int nf = 0; nf < 2; ++nf){
            int b = nf*16 + (lane & 15);
            short4 o;
            float uu0 = bf2f(u_s[b][tb2+0]);
            float uu1 = bf2f(u_s[b][tb2+1]);
            float uu2 = bf2f(u_s[b][tb2+2]);
            float uu3 = bf2f(u_s[b][tb2+3]);
            o.x = bfbits(gelu_f(fmaf(dv, uu0, acc[mi][nf][0])));
            o.y = bfbits(gelu_f(fmaf(dv, uu1, acc[mi][nf][1])));
            o.z = bfbits(gelu_f(fmaf(dv, uu2, acc[mi][nf][2])));
            o.w = bfbits(gelu_f(fmaf(dv, uu3, acc[mi][nf][3])));
            *(short4*)((short*)g + ((size_t)b*H + h)*TLEN + tb2) = o;
        }
    }
}

// ---------------- bf16 transpose (B,H,T) -> (B,T,H) ----------------
__global__ __launch_bounds__(256) void k_trcast_bf(const __hip_bfloat16* __restrict__ x,
                                                   __hip_bfloat16* __restrict__ y){
    __shared__ __hip_bfloat16 tile[32][34];
    int t0 = blockIdx.x*32, h0 = blockIdx.y*32, b = blockIdx.z;
    int tx = threadIdx.x & 31, ty = threadIdx.x >> 5;
    #pragma unroll
    for (int i=0;i<32;i+=8)
        tile[ty+i][tx] = x[((size_t)(b*H + h0+ty+i))*TLEN + t0+tx];
    __syncthreads();
    #pragma unroll
    for (int i=0;i<32;i+=8)
        y[((size_t)(b*TLEN + t0+ty+i))*H + h0+tx] = tile[tx][ty+i];
}

// ---------------- transpose (b,t,h) -> (b,h,t) f32 ----------------
__global__ __launch_bounds__(256) void k_transpose(const float* __restrict__ x, float* __restrict__ xT){
    __shared__ float tile[32][33];
    int t0 = blockIdx.x*32, h0 = blockIdx.y*32, b = blockIdx.z;
    int tx = threadIdx.x & 31, ty = threadIdx.x >> 5;
    #pragma unroll
    for (int i=0;i<32;i+=8)
        tile[ty+i][tx] = x[((size_t)(b*TLEN + t0+ty+i))*H + h0+tx];
    __syncthreads();
    #pragma unroll
    for (int i=0;i<32;i+=8)
        xT[((size_t)(b*H + h0+ty+i))*TLEN + t0+tx] = tile[tx][ty+i];
}

// ---------------- W (L,H,2H) f32 -> Wt (L,2H,H) bf16 ----------------
__global__ __launch_bounds__(256) void k_wtr(const float* __restrict__ W,
                                             __hip_bfloat16* __restrict__ Wt){
    __shared__ float tile[32][33];
    int n0 = blockIdx.x*32, k0 = blockIdx.y*32, l = blockIdx.z;
    const float* Wl = W + (size_t)l*H*H2;
    __hip_bfloat16* Wtl = Wt + (size_t)l*H*H2;
    int tx = threadIdx.x & 31, ty = threadIdx.x >> 5;
    #pragma unroll
    for (int i=0;i<32;i+=8)
        tile[ty+i][tx] = Wl[(size_t)(k0+ty+i)*H2 + n0+tx];
    __syncthreads();
    #pragma unroll
    for (int i=0;i<32;i+=8)
        Wtl[(size_t)(n0+ty+i)*H + k0+tx] = __float2bfloat16(tile[tx][ty+i]);
}

// ---------------- bf16 MFMA GEMM + bias + GLU fused (encoder) ----------------
__global__ __launch_bounds__(256) void k_gemm_glu_mfma(
        const __hip_bfloat16* __restrict__ Abf,
        const __hip_bfloat16* __restrict__ Wt,
        const float* __restrict__ bias2,         // (2048,)
        float* __restrict__ glu){                // (M,1024)
    __shared__ alignas(16) short As[128*32];
    __shared__ alignas(16) short Bs[128*32];
    const int K = 1024;
    int tid = threadIdx.x;
    int lane = tid & 63, wid = tid >> 6;
    int m0 = blockIdx.x * 128;
    int nb = blockIdx.y * 64;
    int g0 = tid, g1 = tid + 256;
    int r0 = g0 >> 2, r1 = g1 >> 2;
    int wtr0 = nb + ((r0>>6)<<5) + (r0&31) + ((r0>>5)&1)*1024;
    int wtr1 = nb + ((r1>>6)<<5) + (r1&31) + ((r1>>5)&1)*1024;
    const short* Ap = (const short*)Abf;
    const short* Bp = (const short*)Wt;
    const short* Ag0 = Ap + (size_t)(m0 + r0)*K + (g0&3)*8;
    const short* Ag1 = Ap + (size_t)(m0 + r1)*K + (g1&3)*8;
    const short* Bg0 = Bp + (size_t)wtr0*K + (g0&3)*8;
    const short* Bg1 = Bp + (size_t)wtr1*K + (g1&3)*8;
    char* AsB = (char*)As;
    char* BsB = (char*)Bs;
    int wr = wid >> 1, wc = wid & 1;
    int mo = wr*64, no = wc*64;
    f32x4 acc[4][4] = {};
    int arow = (lane & 15)*32 + (lane>>4)*8;
    for (int k0 = 0; k0 < K; k0 += 32){
        gload16(Ag0 + k0, AsB + wid*1024);
        gload16(Ag1 + k0, AsB + 4096 + wid*1024);
        gload16(Bg0 + k0, BsB + wid*1024);
        gload16(Bg1 + k0, BsB + 4096 + wid*1024);
        asm volatile("s_waitcnt vmcnt(0)" ::: "memory");
        __syncthreads();
        bf16x8 a[4], b[4];
        #pragma unroll
        for (int mi=0;mi<4;mi++)
            a[mi] = *(const bf16x8*)(As + (mo + mi*16)*32 + arow);
        #pragma unroll
        for (int ni=0;ni<4;ni++)
            b[ni] = *(const bf16x8*)(Bs + (no + ni*16)*32 + arow);
        #pragma unroll
        for (int mi=0;mi<4;mi++){
            #pragma unroll
            for (int ni=0;ni<4;ni++){
                acc[mi][ni] = __builtin_amdgcn_mfma_f32_16x16x32_bf16(a[mi], b[ni], acc[mi][ni], 0, 0, 0);
            }
        }
        __syncthreads();
    }
    int cbase = nb + wc*32 + (lane&15);
    #pragma unroll
    for (int ni=0;ni<2;ni++){
        int c = cbase + ni*16;
        float ba = bias2[c], bb = bias2[c+1024];
        #pragma unroll
        for (int mi=0;mi<4;mi++){
            #pragma unroll
            for (int r=0;r<4;r++){
                size_t m = m0 + mo + mi*16 + (lane>>4)*4 + r;
                float za = acc[mi][ni][r] + ba;
                float zb = acc[mi][ni+2][r] + bb;
                glu[m*H + c] = za * sigm_f(zb);
            }
        }
    }
}

// ---------------- LayerNorm over H per (b,t) row (encoder) ----------------
__global__ __launch_bounds__(256) void k_ln(const float* __restrict__ glu, const float* __restrict__ res,
        const float* __restrict__ gamma, const float* __restrict__ beta, float* __restrict__ outx){
    __shared__ float red[8];
    int row = blockIdx.x;
    int tid = threadIdx.x;
    float4 gv = *(const float4*)(glu + (size_t)row*H + tid*4);
    float4 rv = *(const float4*)(res + (size_t)row*H + tid*4);
    float x0=gv.x+rv.x, x1=gv.y+rv.y, x2=gv.z+rv.z, x3=gv.w+rv.w;
    float s = x0+x1+x2+x3;
    float q = x0*x0+x1*x1+x2*x2+x3*x3;
    #pragma unroll
    for (int m=32;m>=1;m>>=1){ s += __shfl_xor(s,m,64); q += __shfl_xor(q,m,64); }
    int wv = tid>>6;
    if ((tid&63)==0){ red[wv]=s; red[4+wv]=q; }
    __syncthreads();
    s = red[0]+red[1]+red[2]+red[3];
    q = red[4]+red[5]+red[6]+red[7];
    float m = s*(1.0f/H);
    float v = q*(1.0f/H) - m*m;
    float rstd = rsqrtf(v + 1e-5f);
    float4 gm = *(const float4*)(gamma + tid*4);
    float4 bt = *(const float4*)(beta + tid*4);
    float4 o;
    o.x = (x0-m)*rstd*gm.x + bt.x;
    o.y = (x1-m)*rstd*gm.y + bt.y;
    o.z = (x2-m)*rstd*gm.z + bt.z;
    o.w = (x3-m)*rstd*gm.w + bt.w;
    *(float4*)(outx + (size_t)row*H + tid*4) = o;
}

__global__ void k_ctx(const float* __restrict__ x, float* __restrict__ ctx){
    int i = blockIdx.x*256+threadIdx.x;
    int b = i>>10, h = i&(H-1);
    ctx[i] = x[((size_t)(b*TLEN + TLEN-1))*H + h];
}

// ======================= GROUP-LOCAL DECODE, 4 BATCHES/GROUP =======================
__device__ __forceinline__ void gbar_grp(int* gfl, int jj, int g, int tid){
    __syncthreads();
    if (tid == 0)
        __hip_atomic_store(gfl + jj*FLAGSTRIDE, g, __ATOMIC_RELAXED,
                           __HIP_MEMORY_SCOPE_AGENT);
    if (tid < 32){
        int it = 0;
        while (__hip_atomic_load(gfl + tid*FLAGSTRIDE, __ATOMIC_RELAXED,
                                 __HIP_MEMORY_SCOPE_AGENT) < g){
            __builtin_amdgcn_s_sleep(1);
            if (++it > 1000000) break;
        }
    }
    __syncthreads();
}

__device__ __forceinline__ void gemv4(int grp, int jj, int tid,
        float (*ysh)[H], float (*part)[32][8],
        const short* __restrict__ Wl, const float* __restrict__ b2,
        const float* __restrict__ ygel, float* __restrict__ glud){
    #pragma unroll
    for (int i=0;i<16;i++){
        int idx = i*256 + tid;
        int b4 = idx >> 10, hh = idx & 1023;
        ysh[b4][hh] = ald(&ygel[(size_t)(4*grp + b4)*H + hh]);
    }
    __syncthreads();
    int p = tid & 31, ks = tid >> 5;
    int colp = jj*32 + p;
    const short* wza = Wl + (size_t)colp*H + ks*128;
    const short* wzb = Wl + (size_t)(colp+1024)*H + ks*128;
    float a0=0,a1=0,a2=0,a3=0, c0=0,c1=0,c2=0,c3=0;
    const float* u0 = &ysh[0][ks*128];
    const float* u1 = &ysh[1][ks*128];
    const float* u2 = &ysh[2][ks*128];
    const float* u3 = &ysh[3][ks*128];
    for (int kk=0; kk<128; kk+=8){
        bf16x8 wa = *(const bf16x8*)(wza + kk);
        bf16x8 wb = *(const bf16x8*)(wzb + kk);
        #pragma unroll
        for (int j=0;j<8;j++){
            float wav = bf2f(wa[j]), wbv = bf2f(wb[j]);
            float y0 = u0[kk+j], y1 = u1[kk+j], y2 = u2[kk+j], y3 = u3[kk+j];
            a0 = fmaf(y0, wav, a0);  c0 = fmaf(y0, wbv, c0);
            a1 = fmaf(y1, wav, a1);  c1 = fmaf(y1, wbv, c1);
            a2 = fmaf(y2, wav, a2);  c2 = fmaf(y2, wbv, c2);
            a3 = fmaf(y3, wav, a3);  c3 = fmaf(y3, wbv, c3);
        }
    }
    __syncthreads();
    part[ks][p][0]=a0; part[ks][p][1]=c0;
    part[ks][p][2]=a1; part[ks][p][3]=c1;
    part[ks][p][4]=a2; part[ks][p][5]=c2;
    part[ks][p][6]=a3; part[ks][p][7]=c3;
    __syncthreads();
    if (tid < 128){
        int p2 = tid & 31, b4 = tid >> 5;
        int c2 = jj*32 + p2;
        float sa=0.f, sb=0.f;
        #pragma unroll
        for (int q=0;q<8;q++){ sa += part[q][p2][b4*2]; sb += part[q][p2][b4*2+1]; }
        float za = sa + b2[c2];
        float zb = sb + b2[1024 + c2];
        ast(&glud[(size_t)(4*grp + b4)*H + c2], za * sigm_f(zb));
    }
}

__global__ __launch_bounds__(256, 1) void k_decode(
        const float* __restrict__ Kbuf, const float* __restrict__ Dv,
        const __hip_bfloat16* __restrict__ Wt, const float* __restrict__ bias2,
        const float* __restrict__ lng, const float* __restrict__ lnb,
        const float* __restrict__ ctx, const float* __restrict__ headw,
        const float* __restrict__ headb,
        float* __restrict__ ygel0, float* __restrict__ ygel1,
        float* __restrict__ glud0, float* __restrict__ glud1,
        float* __restrict__ out, int* __restrict__ flags){
    __shared__ float hist[16][H];
    __shared__ float ysh[4][H];
    __shared__ float part[8][32][8];
    __shared__ float red[8];
    __shared__ float bitsh[16];
    int bid = blockIdx.x;
    int grp = bid & 7, jj = bid >> 3;
    int tid = threadIdx.x;
    int lane = tid & 63, wv = tid >> 6;
    bool leader = (jj < 4);
    int b = grp*4 + jj;
    float4 dv0v, dv1v, lg0v, be0v, lg1v, be1v, cvxv, hwv;
    float hb = headb[0];
    if (leader){
        dv0v = *(const float4*)(Dv + tid*4);
        dv1v = *(const float4*)(Dv + H + tid*4);
        lg0v = *(const float4*)(lng + tid*4);
        be0v = *(const float4*)(lnb + tid*4);
        lg1v = *(const float4*)(lng + H + tid*4);
        be1v = *(const float4*)(lnb + H + tid*4);
        cvxv = *(const float4*)(ctx + (size_t)b*H + tid*4);
        hwv  = *(const float4*)(headw + tid*4);
    }
    if (tid < 16) bitsh[tid] = 0.f;
    __syncthreads();
    const short* Wt0 = (const short*)Wt;
    const short* Wt1 = (const short*)Wt + (size_t)H*H2;
    int* gfl = flags + grp*32*FLAGSTRIDE;
    int g = 1;
    for (int s=0; s<NSTEPS; s++){
        if (leader){
            if (s > 0){
                int sp = s-1;
                float x0 = ald(&glud1[(size_t)b*H + tid*4+0]);
                float x1 = ald(&glud1[(size_t)b*H + tid*4+1]);
                float x2 = ald(&glud1[(size_t)b*H + tid*4+2]);
                float x3 = ald(&glud1[(size_t)b*H + tid*4+3]);
                if (sp != 0){ x0*=2.f; x1*=2.f; x2*=2.f; x3*=2.f; }
                float su = x0+x1+x2+x3, qu = x0*x0+x1*x1+x2*x2+x3*x3;
                #pragma unroll
                for (int m=32;m>=1;m>>=1){ su += __shfl_xor(su,m,64); qu += __shfl_xor(qu,m,64); }
                if (lane==0){ red[wv]=su; red[4+wv]=qu; }
                __syncthreads();
                float S = red[0]+red[1]+red[2]+red[3];
                float Q = red[4]+red[5]+red[6]+red[7];
                float mean = S*(1.f/H), var = Q*(1.f/H)-mean*mean;
                float rstd = rsqrtf(var + 1e-5f);
                float d0 = (x0-mean)*rstd*lg1v.x + be1v.x + cvxv.x;
                float d1 = (x1-mean)*rstd*lg1v.y + be1v.y + cvxv.y;
                float d2 = (x2-mean)*rstd*lg1v.z + be1v.z + cvxv.z;
                float d3 = (x3-mean)*rstd*lg1v.w + be1v.w + cvxv.w;
                float hp = d0*hwv.x + d1*hwv.y + d2*hwv.z + d3*hwv.w;
                #pragma unroll
                for (int m=32;m>=1;m>>=1) hp += __shfl_xor(hp,m,64);
                __syncthreads();
                if (lane==0) red[wv] = hp;
                __syncthreads();
                float hs = red[0]+red[1]+red[2]+red[3] + hb;
                float bit = sigm_f(hs);
                if (tid==0){ out[b*NSTEPS + sp] = bit; bitsh[sp] = bit; }
                __syncthreads();
            }
            float bu = (s==0) ? 0.f : bitsh[s-1];
            float dvs[4] = {dv0v.x, dv0v.y, dv0v.z, dv0v.w};
            #pragma unroll
            for (int i=0;i<4;i++){
                int h = tid*4+i;
                const float* Kr = Kbuf + (size_t)h*TLEN;
                float y0 = dvs[i]*bu;
                #pragma unroll
                for (int d=0; d<16; d++){
                    int idx = s-1-d;
                    float uv = (idx >= 0) ? bitsh[idx] : 0.f;
                    y0 = fmaf(Kr[d], uv, y0);
                }
                ast(&ygel0[(size_t)b*H + h], gelu_f(y0));
            }
        }
        gbar_grp(gfl, jj, g++, tid);
        gemv4(grp, jj, tid, ysh, part, Wt0, bias2, ygel0, glud0);
        gbar_grp(gfl, jj, g++, tid);
        if (leader){
            float x0 = ald(&glud0[(size_t)b*H + tid*4+0]);
            float x1 = ald(&glud0[(size_t)b*H + tid*4+1]);
            float x2 = ald(&glud0[(size_t)b*H + tid*4+2]);
            float x3 = ald(&glud0[(size_t)b*H + tid*4+3]);
            if (s != 0){ x0*=2.f; x1*=2.f; x2*=2.f; x3*=2.f; }
            float su = x0+x1+x2+x3, qu = x0*x0+x1*x1+x2*x2+x3*x3;
            #pragma unroll
            for (int m=32;m>=1;m>>=1){ su += __shfl_xor(su,m,64); qu += __shfl_xor(qu,m,64); }
            if (lane==0){ red[wv]=su; red[4+wv]=qu; }
            __syncthreads();
            float S = red[0]+red[1]+red[2]+red[3];
            float Q = red[4]+red[5]+red[6]+red[7];
            float mean = S*(1.f/H), var = Q*(1.f/H)-mean*mean;
            float rstd = rsqrtf(var + 1e-5f);
            float dd[4];
            dd[0] = (x0-mean)*rstd*lg0v.x + be0v.x;
            dd[1] = (x1-mean)*rstd*lg0v.y + be0v.y;
            dd[2] = (x2-mean)*rstd*lg0v.z + be0v.z;
            dd[3] = (x3-mean)*rstd*lg0v.w + be0v.w;
            float dvs[4] = {dv1v.x, dv1v.y, dv1v.z, dv1v.w};
            #pragma unroll
            for (int i=0;i<4;i++){
                int h = tid*4+i;
                hist[s & 15][h] = dd[i];
                const float* Kr = Kbuf + (size_t)(H+h)*TLEN;
                float y1 = dvs[i]*dd[i];
                #pragma unroll
                for (int d=0; d<16; d++){
                    int sd = s-d;
                    float uv = (sd >= 0) ? hist[sd & 15][h] : 0.f;
                    y1 = fmaf(Kr[d], uv, y1);
                }
                ast(&ygel1[(size_t)b*H + h], gelu_f(y1));
            }
        }
        gbar_grp(gfl, jj, g++, tid);
        gemv4(grp, jj, tid, ysh, part, Wt1, bias2 + H2, ygel1, glud1);
        gbar_grp(gfl, jj, g++, tid);
    }
    if (leader){
        float x0 = 2.f*ald(&glud1[(size_t)b*H + tid*4+0]);
        float x1 = 2.f*ald(&glud1[(size_t)b*H + tid*4+1]);
        float x2 = 2.f*ald(&glud1[(size_t)b*H + tid*4+2]);
        float x3 = 2.f*ald(&glud1[(size_t)b*H + tid*4+3]);
        float su = x0+x1+x2+x3, qu = x0*x0+x1*x1+x2*x2+x3*x3;
        #pragma unroll
        for (int m=32;m>=1;m>>=1){ su += __shfl_xor(su,m,64); qu += __shfl_xor(qu,m,64); }
        if (lane==0){ red[wv]=su; red[4+wv]=qu; }
        __syncthreads();
        float S = red[0]+red[1]+red[2]+red[3];
        float Q = red[4]+red[5]+red[6]+red[7];
        float mean = S*(1.f/H), var = Q*(1.f/H)-mean*mean;
        float rstd = rsqrtf(var + 1e-5f);
        float d0 = (x0-mean)*rstd*lg1v.x + be1v.x + cvxv.x;
        float d1 = (x1-mean)*rstd*lg1v.y + be1v.y + cvxv.y;
        float d2 = (x2-mean)*rstd*lg1v.z + be1v.z + cvxv.z;
        float d3 = (x3-mean)*rstd*lg1v.w + be1v.w + cvxv.w;
        float hp = d0*hwv.x + d1*hwv.y + d2*hwv.z + d3*hwv.w;
        #pragma unroll
        for (int m=32;m>=1;m>>=1) hp += __shfl_xor(hp,m,64);
        __syncthreads();
        if (lane==0) red[wv] = hp;
        __syncthreads();
        float hs = red[0]+red[1]+red[2]+red[3] + hb;
        if (tid==0) out[b*NSTEPS + 15] = sigm_f(hs);
    }
}

extern "C" void kernel_launch(void* const* d_in, const int* in_sizes, int n_in,
                              void* d_out, int out_size, void* d_ws, size_t ws_size,
                              hipStream_t stream) {
    const float* in_seq = (const float*)d_in[0];
    const float* inw  = (const float*)d_in[2];
    const float* inb  = (const float*)d_in[3];
    const float* log_dt = (const float*)d_in[4];
    const float* Are = (const float*)d_in[5];
    const float* Aim = (const float*)d_in[6];
    const float* Bre = (const float*)d_in[7];
    const float* Bim = (const float*)d_in[8];
    const float* Cre = (const float*)d_in[9];
    const float* Cim = (const float*)d_in[10];
    const float* Dv  = (const float*)d_in[11];
    const float* outw = (const float*)d_in[12];
    const float* outb = (const float*)d_in[13];
    const float* lng = (const float*)d_in[14];
    const float* lnb = (const float*)d_in[15];
    const float* headw = (const float*)d_in[16];
    const float* headb = (const float*)d_in[17];
    float* out = (float*)d_out;

    float* ws = (float*)d_ws;
    size_t off = 0;
    auto alloc = [&](size_t n){ float* p = ws + off; off += n; return p; };
    float* dAr = alloc((size_t)LAYN*H*NST);
    float* dAi = alloc((size_t)LAYN*H*NST);
    float* dBr = alloc((size_t)LAYN*H*NST);
    float* dBi = alloc((size_t)LAYN*H*NST);
    float* Kbuf = alloc((size_t)LAYN*H*TLEN);
    float* bufA = alloc((size_t)BSZ*TLEN*H);                              // 67MB
    float* bufB = alloc((size_t)BSZ*TLEN*H);                              // 67MB
    __hip_bfloat16* gbf = (__hip_bfloat16*)alloc((size_t)BSZ*TLEN*H/2);   // 33.5MB
    __hip_bfloat16* Abf = (__hip_bfloat16*)alloc((size_t)BSZ*TLEN*H/2);   // 33.5MB
    __hip_bfloat16* Wt  = (__hip_bfloat16*)alloc((size_t)LAYN*H*H2/2);    // 8.4MB
    float* ctx = alloc((size_t)BSZ*H);
    float* ygel0 = alloc((size_t)BSZ*H);
    float* ygel1 = alloc((size_t)BSZ*H);
    float* glud0 = alloc((size_t)BSZ*H);
    float* glud1 = alloc((size_t)BSZ*H);
    int*   flags = (int*)alloc((size_t)NGRP*32*FLAGSTRIDE);
    // total ~217 MB (round-3's proven 241.7 MB OK; round-4's 283.6 MB crashed)

    k_precompute<<<(LAYN*H*NST+255)/256, 256, 0, stream>>>(log_dt,Are,Aim,Bre,Bim,dAr,dAi,dBr,dBi);
    k_genK<<<LAYN*H, 64, 0, stream>>>(dAr,dAi,dBr,dBi,Cre,Cim,Kbuf);
    k_wtr<<<dim3(H2/32, H/32, LAYN), 256, 0, stream>>>(outw, Wt);
    k_inproj_x <<<(BSZ*TLEN*H)/256, 256, 0, stream>>>(in_seq, inw, inb, bufA);
    k_inproj_xT<<<(BSZ*TLEN*H)/256, 256, 0, stream>>>(in_seq, inw, inb, bufB);

    // ---- layer 0: res = bufA (b,t,h); xT = bufB (b,h,t)
    k_conv_mfma<<<dim3(H), 256, 0, stream>>>(bufB, Kbuf, Dv, gbf, 0);
    k_trcast_bf<<<dim3(TLEN/32, H/32, BSZ), 256, 0, stream>>>(gbf, Abf);
    k_gemm_glu_mfma<<<dim3(BSZ*TLEN/128, H/64), 256, 0, stream>>>(Abf, Wt, outb, bufB);
    k_ln<<<BSZ*TLEN, 256, 0, stream>>>(bufB, bufA, lng, lnb, bufA);
    k_transpose<<<dim3(16,32,32), 256, 0, stream>>>(bufA, bufB);

    // ---- layer 1
    k_conv_mfma<<<dim3(H), 256, 0, stream>>>(bufB, Kbuf, Dv, gbf, 1);
    k_trcast_bf<<<dim3(TLEN/32, H/32, BSZ), 256, 0, stream>>>(gbf, Abf);
    k_gemm_glu_mfma<<<dim3(BSZ*TLEN/128, H/64), 256, 0, stream>>>(Abf, Wt + (size_t)H*H2, outb + H2, bufB);
    k_ln<<<BSZ*TLEN, 256, 0, stream>>>(bufB, bufA, lng+H, lnb+H, bufA);

    k_ctx<<<(BSZ*H)/256, 256, 0, stream>>>(bufA, ctx);

    // ---- decode: 8 same-XCD groups x 4 batches, group-local barriers
    hipMemsetAsync(flags, 0, sizeof(int)*(size_t)NGRP*32*FLAGSTRIDE, stream);
    k_decode<<<NGRP*32, 256, 0, stream>>>(Kbuf, Dv, Wt, outb, lng, lnb,
                                          ctx, headw, headb,
                                          ygel0, ygel1, glud0, glud1, out, flags);
}